// Round 11
// baseline (1161.376 us; speedup 1.0000x reference)
//
#include <hip/hip_runtime.h>

// PCmer forward: bf16-MFMA; phi_k fused INTO ctx (kp never hits HBM); phi_q+dinv+attn_out fused;
// GLU fused into pw1 (interleaved weights); fused QKV; ksum fused into ctx.
// R1: attn LDS 76->30KB; R2/R3: GEMM counted-vmcnt pipeline; R6: __expf epilogues;
// R7: attn q-in-regs + coalesced o-write; R9: gemm_sm 64x128 for wo/pw2;
// R10: ln wave-per-token (1136.2us = best).
// R11: ONE change vs R10 -- attn PV loop: hoist the 4 ctx B-fragment global loads to the TOP
//      of each m0 iteration (before the FAVOR epilogue). Epilogue VALU (~200cy) now covers L2
//      latency. Zero extra registers (bfr[4] lifetime just starts earlier; R8's rotate-prefetch
//      spilled because it ADDED 32 persistent VGPRs).
// L=6, B=4, N=2048, D=512, H=8, DH=64, ID=512, M=266, INNER=1024, K=31.

#define L_LAYERS 6
#define B_ 4
#define N_ 2048
#define D_ 512
#define H_ 8
#define DH_ 64
#define M_ 266
#define INNER_ 1024
#define T_ 8192            // B*N tokens
#define PS_ 320            // padded m stride (zeros in [266,320))
#define QKVS_ 1536         // qkv row stride
#define NS_ 8              // ctx n-splits

typedef __attribute__((ext_vector_type(8))) short short8;
typedef __attribute__((ext_vector_type(4))) float floatx4;

__device__ __forceinline__ ushort f2bf(float f) {
  union { float f; uint u; } v; v.f = f;
  uint r = v.u + 0x7fffu + ((v.u >> 16) & 1u);
  return (ushort)(r >> 16);
}
__device__ __forceinline__ float bf2f(ushort u) {
  union { uint u; float f; } v; v.u = ((uint)u) << 16;
  return v.f;
}
__device__ __forceinline__ float wave_sum(float v) {
#pragma unroll
  for (int m = 1; m < 64; m <<= 1) v += __shfl_xor(v, m);
  return v;
}
// async global->LDS, 16B per lane; dest = wave-uniform base + lane*16 (src per-lane)
__device__ __forceinline__ void async_cp16(const void* g, void* l) {
  __builtin_amdgcn_global_load_lds(
      (const __attribute__((address_space(1))) void*)g,
      (__attribute__((address_space(3))) void*)l, 16, 0, 0);
}

// ---------------- weight packing (consolidated) ----------------
__global__ void f2bf4_dual(const float4* __restrict__ s1, int n1,
                           const float4* __restrict__ s2, int n2,
                           ushort* __restrict__ out) {
  int i = blockIdx.x * 256 + threadIdx.x;
  if (i >= n1 + n2) return;
  float4 v = (i < n1) ? s1[i] : s2[i - n1];
  ushort4 r;
  r.x = f2bf(v.x); r.y = f2bf(v.y); r.z = f2bf(v.z); r.w = f2bf(v.w);
  *(ushort4*)(out + (size_t)i * 4) = r;
}
__global__ void pack_qkv_w3(const float4* __restrict__ wq, const float4* __restrict__ wk,
                            const float4* __restrict__ wv, ushort* __restrict__ dst) {
  int i = blockIdx.x * 256 + threadIdx.x;     // 3*L*512*128
  const int per = L_LAYERS * 512 * 128;
  if (i >= 3 * per) return;
  int seg = i / per;
  int rem = i - seg * per;
  const float4* src = seg == 0 ? wq : (seg == 1 ? wk : wv);
  int l = rem >> 16;
  int r2 = rem & 65535;
  int row = r2 >> 7, c4 = r2 & 127;
  float4 v = src[rem];
  ushort4 r;
  r.x = f2bf(v.x); r.y = f2bf(v.y); r.z = f2bf(v.z); r.w = f2bf(v.w);
  *(ushort4*)(dst + ((size_t)l * QKVS_ + seg * 512 + row) * 512 + c4 * 4) = r;
}
// qkv bias + padded proj + pw1 bias in one kernel (range select)
__global__ void pack_small(const float* __restrict__ bq, const float* __restrict__ bk,
                           const float* __restrict__ bv, float* __restrict__ bqkv,
                           const float* __restrict__ proj, ushort* __restrict__ pjp,
                           const float* __restrict__ pw1b, float* __restrict__ pb1) {
  int i = blockIdx.x * 256 + threadIdx.x;
  const int A = L_LAYERS * QKVS_;            // 9216
  const int Bn = L_LAYERS * 320 * 64;        // 122880
  const int C = L_LAYERS * 2048;             // 12288
  if (i < A) {
    int l = i / QKVS_, c = i % QKVS_;
    bqkv[i] = c < 512 ? bq[l * 512 + c]
                      : (c < 1024 ? bk[l * 512 + c - 512] : bv[l * 512 + c - 1024]);
  } else if (i < A + Bn) {
    int j = i - A;
    int l = j / (320 * 64), rem = j % (320 * 64), m = rem >> 6, kk = rem & 63;
    pjp[j] = (m < M_) ? f2bf(proj[((size_t)l * M_ + m) * 64 + kk]) : (ushort)0;
  } else if (i < A + Bn + C) {
    int j = i - A - Bn;
    int l = j >> 11, cp = j & 2047;
    int s = (cp >> 4) & 1;
    int srow = ((cp >> 5) << 4) + (cp & 15) + s * 1024;
    pb1[j] = pw1b[l * 2048 + srow];
  }
}
// pw1 interleave: out col c' = 32b+16s+j16 -> src row s*1024 + 16b + j16
__global__ void pack_pw1_w(const float4* __restrict__ src, ushort* __restrict__ dst) {
  int i = blockIdx.x * 256 + threadIdx.x;   // L*2048*128
  if (i >= L_LAYERS * 2048 * 128) return;
  int l = i >> 18;
  int rem = i & 262143;
  int cp = rem >> 7, c4 = rem & 127;
  int s = (cp >> 4) & 1;
  int srow = ((cp >> 5) << 4) + (cp & 15) + s * 1024;
  float4 v = src[((size_t)l * 2048 + srow) * 128 + c4];
  ushort4 r;
  r.x = f2bf(v.x); r.y = f2bf(v.y); r.z = f2bf(v.z); r.w = f2bf(v.w);
  *(ushort4*)(dst + ((size_t)l * 2048 + cp) * 512 + c4 * 4) = r;
}

// ---------------- layernorm: wave per token (D=512 = 8 f32/lane), no LDS/barriers ----------
__global__ __launch_bounds__(256) void ln_kernel(const float* __restrict__ x,
                                                 const float* __restrict__ g,
                                                 const float* __restrict__ b,
                                                 ushort* __restrict__ out) {
  const int w = threadIdx.x >> 6, lane = threadIdx.x & 63;
  const int t = blockIdx.x * 4 + w;
  const float4* row = (const float4*)(x + (size_t)t * D_);
  float4 v0 = row[lane * 2];
  float4 v1 = row[lane * 2 + 1];
  float s1 = v0.x + v0.y + v0.z + v0.w + v1.x + v1.y + v1.z + v1.w;
  float s2 = v0.x * v0.x + v0.y * v0.y + v0.z * v0.z + v0.w * v0.w +
             v1.x * v1.x + v1.y * v1.y + v1.z * v1.z + v1.w * v1.w;
  s1 = wave_sum(s1);
  s2 = wave_sum(s2);
  float mu = s1 * (1.f / D_);
  float var = s2 * (1.f / D_) - mu * mu;
  float rs = rsqrtf(var + 1e-5f);
  float4 g0 = ((const float4*)g)[lane * 2];
  float4 g1 = ((const float4*)g)[lane * 2 + 1];
  float4 b0 = ((const float4*)b)[lane * 2];
  float4 b1 = ((const float4*)b)[lane * 2 + 1];
  float vv[8] = {v0.x, v0.y, v0.z, v0.w, v1.x, v1.y, v1.z, v1.w};
  float gg[8] = {g0.x, g0.y, g0.z, g0.w, g1.x, g1.y, g1.z, g1.w};
  float bb[8] = {b0.x, b0.y, b0.z, b0.w, b1.x, b1.y, b1.z, b1.w};
  ushort o8[8];
#pragma unroll
  for (int j = 0; j < 8; j++)
    o8[j] = f2bf((vv[j] - mu) * rs * gg[j] + bb[j]);
  *(short8*)(out + (size_t)t * D_ + lane * 8) = *(const short8*)o8;
}

// ---------------- bf16 MFMA GEMM 128x128: BUFS-deep pipeline, counted vmcnt ----------------
// BUFS=3: depth-2, 48KB (use when grid <= 3 blocks/CU). BUFS=2: depth-1, 32KB (grid = 4/CU).
template <bool HAS_RES, bool OUT_BF16, int ACT, int KT, int BUFS>
__global__ __launch_bounds__(256) void gemm_mfma(const ushort* __restrict__ A,
                                                 const ushort* __restrict__ W,
                                                 const float* __restrict__ bias,
                                                 const float* __restrict__ res,
                                                 void* __restrict__ Cout,
                                                 int ldc) {
  constexpr int NT = KT / 32;
  __shared__ ushort As[BUFS][128 * 32];
  __shared__ ushort Bs[BUFS][128 * 32];
  const int tid = threadIdx.x;
  const int w = tid >> 6, lane = tid & 63;
  const int row0 = blockIdx.x * 128, col0 = blockIdx.y * 128;
  const int rl = lane >> 2;
  const int lc = ((lane & 3) ^ ((lane >> 3) & 3)) * 8;
  const ushort* gA0 = A + (size_t)(row0 + w * 32 + rl) * KT + lc;
  const ushort* gA1 = gA0 + (size_t)16 * KT;
  const ushort* gB0 = W + (size_t)(col0 + w * 32 + rl) * KT + lc;
  const ushort* gB1 = gB0 + (size_t)16 * KT;
  const int m16 = lane & 15, quad = lane >> 4;
  const int awr = (w >> 1) * 64, bwc = (w & 1) * 64;
  floatx4 acc[4][4] = {};

  auto stage = [&](int t, int buf) {
    async_cp16(gA0 + t * 32, As[buf] + w * 1024);
    async_cp16(gA1 + t * 32, As[buf] + w * 1024 + 512);
    async_cp16(gB0 + t * 32, Bs[buf] + w * 1024);
    async_cp16(gB1 + t * 32, Bs[buf] + w * 1024 + 512);
  };
  auto body = [&](int buf, bool bar2) {
    short8 af[4], bfr[4];
#pragma unroll
    for (int i = 0; i < 4; i++) {
      int r = awr + i * 16 + m16;
      af[i] = *(const short8*)&As[buf][r * 32 + (quad ^ ((r >> 1) & 3)) * 8];
    }
#pragma unroll
    for (int j = 0; j < 4; j++) {
      int r = bwc + j * 16 + m16;
      bfr[j] = *(const short8*)&Bs[buf][r * 32 + (quad ^ ((r >> 1) & 3)) * 8];
    }
    if (bar2) {
      asm volatile("s_waitcnt lgkmcnt(0)" ::: "memory");
      __builtin_amdgcn_sched_barrier(0);
      __builtin_amdgcn_s_barrier();
    }
#pragma unroll
    for (int i = 0; i < 4; i++)
#pragma unroll
      for (int j = 0; j < 4; j++)
        acc[i][j] = __builtin_amdgcn_mfma_f32_16x16x32_bf16(af[i], bfr[j], acc[i][j], 0, 0, 0);
  };

  stage(0, 0);
  if (BUFS == 3) stage(1, 1);
  int c = 0;
  for (int t = 0; t < NT - (BUFS - 1); t++) {
    int pf = c + (BUFS - 1); if (pf >= BUFS) pf -= BUFS;
    stage(t + BUFS - 1, pf);
    if (BUFS == 3) { asm volatile("s_waitcnt vmcnt(8)" ::: "memory"); }
    else           { asm volatile("s_waitcnt vmcnt(4)" ::: "memory"); }
    __builtin_amdgcn_s_barrier();
    body(c, true);
    c++; if (c >= BUFS) c -= BUFS;
  }
  if (BUFS == 3) {
    asm volatile("s_waitcnt vmcnt(4)" ::: "memory");
    __builtin_amdgcn_s_barrier();
    body(c, false);
    c++; if (c >= BUFS) c -= BUFS;
  }
  asm volatile("s_waitcnt vmcnt(0)" ::: "memory");
  __builtin_amdgcn_s_barrier();
  body(c, false);

  if (ACT == 0) {
#pragma unroll
    for (int i = 0; i < 4; i++) {
      const int r0 = row0 + awr + i * 16 + quad * 4;
#pragma unroll
      for (int j = 0; j < 4; j++) {
        const int cc = col0 + bwc + j * 16 + m16;
        const float bv = bias[cc];
#pragma unroll
        for (int r = 0; r < 4; r++) {
          float vv = acc[i][j][r] + bv;
          if (HAS_RES) vv += res[(size_t)(r0 + r) * ldc + cc];
          if (OUT_BF16) ((ushort*)Cout)[(size_t)(r0 + r) * ldc + cc] = f2bf(vv);
          else          ((float*)Cout)[(size_t)(r0 + r) * ldc + cc] = vv;
        }
      }
    }
  } else {
    // GLU epilogue on interleaved columns: z = (a+ba)*sigmoid(g+bg)
#pragma unroll
    for (int i = 0; i < 4; i++) {
      const int r0 = row0 + awr + i * 16 + quad * 4;
#pragma unroll
      for (int jp = 0; jp < 2; jp++) {
        const int j = jp * 2;
        const int ca = col0 + bwc + j * 16 + m16;
        const float ba = bias[ca], bg = bias[ca + 16];
        const int oc = ((col0 + bwc) >> 1) + jp * 16 + m16;
#pragma unroll
        for (int r = 0; r < 4; r++) {
          float a = acc[i][j][r] + ba;
          float g = acc[i][j + 1][r] + bg;
          float z = a / (1.f + __expf(-g));
          ((ushort*)Cout)[(size_t)(r0 + r) * ldc + oc] = f2bf(z);
        }
      }
    }
  }
}

// ---------------- bf16 MFMA GEMM 64x128: occupancy variant for wo/pw2 ----------------------
// Grid (T/64, 4) = 512 blocks = 2 blocks/CU (vs 1 for 128^2) -- these GEMMs are latency-bound.
// Wave tile 32x64 (acc[2][4]); 3 loads/wave/stage; vmcnt(6)/(3)/(0); 36KB LDS; fp32 out+res.
template <int KT>
__global__ __launch_bounds__(256) void gemm_sm(const ushort* __restrict__ A,
                                               const ushort* __restrict__ W,
                                               const float* __restrict__ bias,
                                               const float* __restrict__ res,
                                               float* __restrict__ Cout,
                                               int ldc) {
  constexpr int NT = KT / 32;
  __shared__ ushort As[3][64 * 32];
  __shared__ ushort Bs[3][128 * 32];
  const int tid = threadIdx.x;
  const int w = tid >> 6, lane = tid & 63;
  const int row0 = blockIdx.x * 64, col0 = blockIdx.y * 128;
  const int rl = lane >> 2;
  const int lc = ((lane & 3) ^ ((lane >> 3) & 3)) * 8;
  const ushort* gA = A + (size_t)(row0 + w * 16 + rl) * KT + lc;
  const ushort* gB0 = W + (size_t)(col0 + w * 32 + rl) * KT + lc;
  const ushort* gB1 = gB0 + (size_t)16 * KT;
  const int m16 = lane & 15, quad = lane >> 4;
  const int awr = (w >> 1) * 32;
  const int bwc = (w & 1) * 64;
  floatx4 acc[2][4] = {};

  auto stage = [&](int t, int buf) {
    async_cp16(gA + t * 32, As[buf] + w * 512);
    async_cp16(gB0 + t * 32, Bs[buf] + w * 1024);
    async_cp16(gB1 + t * 32, Bs[buf] + w * 1024 + 512);
  };
  auto body = [&](int buf, bool bar2) {
    short8 af[2], bfr[4];
#pragma unroll
    for (int i = 0; i < 2; i++) {
      int r = awr + i * 16 + m16;
      af[i] = *(const short8*)&As[buf][r * 32 + (quad ^ ((r >> 1) & 3)) * 8];
    }
#pragma unroll
    for (int j = 0; j < 4; j++) {
      int r = bwc + j * 16 + m16;
      bfr[j] = *(const short8*)&Bs[buf][r * 32 + (quad ^ ((r >> 1) & 3)) * 8];
    }
    if (bar2) {
      asm volatile("s_waitcnt lgkmcnt(0)" ::: "memory");
      __builtin_amdgcn_sched_barrier(0);
      __builtin_amdgcn_s_barrier();
    }
#pragma unroll
    for (int i = 0; i < 2; i++)
#pragma unroll
      for (int j = 0; j < 4; j++)
        acc[i][j] = __builtin_amdgcn_mfma_f32_16x16x32_bf16(af[i], bfr[j], acc[i][j], 0, 0, 0);
  };

  stage(0, 0);
  stage(1, 1);
  int c = 0;
  for (int t = 0; t < NT - 2; t++) {
    int pf = c + 2; if (pf >= 3) pf -= 3;
    stage(t + 2, pf);
    asm volatile("s_waitcnt vmcnt(6)" ::: "memory");
    __builtin_amdgcn_s_barrier();
    body(c, true);
    c++; if (c >= 3) c -= 3;
  }
  asm volatile("s_waitcnt vmcnt(3)" ::: "memory");
  __builtin_amdgcn_s_barrier();
  body(c, false);
  c++; if (c >= 3) c -= 3;
  asm volatile("s_waitcnt vmcnt(0)" ::: "memory");
  __builtin_amdgcn_s_barrier();
  body(c, false);

#pragma unroll
  for (int i = 0; i < 2; i++) {
    const int r0 = row0 + awr + i * 16 + quad * 4;
#pragma unroll
    for (int j = 0; j < 4; j++) {
      const int cc = col0 + bwc + j * 16 + m16;
      const float bv = bias[cc];
#pragma unroll
      for (int r = 0; r < 4; r++)
        Cout[(size_t)(r0 + r) * ldc + cc] =
            acc[i][j][r] + bv + res[(size_t)(r0 + r) * ldc + cc];
    }
  }
}

// ---------------- ctx with phi_k fused: kp computed in-LDS, never hits HBM ----------------
__global__ __launch_bounds__(256) void ctx_phi_mfma(const ushort* __restrict__ qkv,
                                                    const ushort* __restrict__ projp,
                                                    float* __restrict__ part,
                                                    float* __restrict__ kpart) {
  __shared__ ushort projs[64 * 64];  // proj rows m0..m0+63, XOR-chunk layout
  __shared__ ushort kts[32 * 64];    // raw k tile, XOR-chunk layout
  __shared__ ushort kps[64][40];     // phi^T [m][n swizzled]
  __shared__ ushort vsT[64][40];     // v^T  [e][n swizzled]
  __shared__ float diag_sh[32];
  __shared__ float kshare[4][64];
  const int bh = blockIdx.x, mt = blockIdx.y, ns = blockIdx.z;
  const int b = bh >> 3, h = bh & 7;
  const int m0 = mt * 64;
  const int tid = threadIdx.x;
  const int w = tid >> 6, lane = tid & 63, l16 = lane & 15, quad = lane >> 4;
  const int rl8 = lane >> 3;
  const int lc8 = ((lane & 7) ^ (rl8 & 7)) * 8;
#pragma unroll
  for (int j = 0; j < 2; j++) {
    const int rb = w * 16 + j * 8;
    async_cp16(projp + (size_t)(m0 + rb + rl8) * 64 + lc8, projs + rb * 64);
  }
  const int nn = tid >> 3;
  const int a8 = tid & 7;
  const int gn = nn >> 3, jn = nn & 7;
  const int pc = ((gn ^ (a8 & 3)) << 3) | jn;
  const int km = tid & 63, kg = tid >> 6;
  const float dn = 0.35355339059327373f;
  const float ratio = 0.06131393394849658f;
  floatx4 acc[4] = {};
  float ksp = 0.f;
  for (int nstep = 0; nstep < 2048 / NS_ / 32; nstep++) {
    const int n0 = ns * (2048 / NS_) + nstep * 32;
    {
      const int rb = w * 8;
      async_cp16(qkv + (size_t)(b * N_ + n0 + rb + rl8) * QKVS_ + 512 + h * 64 + lc8,
                 kts + rb * 64);
    }
    uint4 vv = *(const uint4*)(qkv + ((size_t)(b * N_ + n0 + nn)) * QKVS_ + 1024 + h * 64 + a8 * 8);
    __syncthreads();
    {
      const int r = tid >> 3;
      const int c = tid & 7;
      short8 kv8 = *(const short8*)&kts[r * 64 + c * 8];
      const ushort* u = (const ushort*)&kv8;
      float s = 0.f;
#pragma unroll
      for (int j = 0; j < 8; j++) { float f = bf2f(u[j]); s += f * f; }
      s += __shfl_xor(s, 1);
      s += __shfl_xor(s, 2);
      s += __shfl_xor(s, 4);
      if ((tid & 7) == 0) diag_sh[r] = 0.0625f * s;
    }
    {
      const ushort* ve = (const ushort*)&vv;
#pragma unroll
      for (int j = 0; j < 8; j++) vsT[a8 * 8 + j][pc] = ve[j];
    }
    __syncthreads();
    floatx4 pacc[2] = {};
    __builtin_amdgcn_s_setprio(1);
#pragma unroll
    for (int s = 0; s < 2; s++) {
      const int ar = w * 16 + l16;
      short8 af = *(const short8*)&projs[ar * 64 + ((s * 4 + quad) ^ (ar & 7)) * 8];
#pragma unroll
      for (int nj = 0; nj < 2; nj++) {
        const int br = nj * 16 + l16;
        short8 bf = *(const short8*)&kts[br * 64 + ((s * 4 + quad) ^ (br & 7)) * 8];
        pacc[nj] = __builtin_amdgcn_mfma_f32_16x16x32_bf16(af, bf, pacc[nj], 0, 0, 0);
      }
    }
    __builtin_amdgcn_s_setprio(0);
#pragma unroll
    for (int nj = 0; nj < 2; nj++) {
      const int n = nj * 16 + l16;
      const float dgn = diag_sh[n];
#pragma unroll
      for (int r = 0; r < 4; r++) {
        const int m = w * 16 + quad * 4 + r;
        float val = (m0 + m < M_) ? ratio * __expf(dn * pacc[nj][r] - dgn + 1e-4f) : 0.f;
        kps[m][(((n >> 3) ^ ((m >> 3) & 3)) << 3) | (n & 7)] = f2bf(val);
      }
    }
    __syncthreads();
    const int am = w * 16 + l16;
    const int apg = quad ^ ((am >> 3) & 3);
    short8 af = *(const short8*)&kps[am][apg * 8];
    __builtin_amdgcn_s_setprio(1);
#pragma unroll
    for (int et = 0; et < 4; et++) {
      const int be = et * 16 + l16;
      const int bpg = quad ^ ((be >> 3) & 3);
      short8 bf = *(const short8*)&vsT[be][bpg * 8];
      acc[et] = __builtin_amdgcn_mfma_f32_16x16x32_bf16(af, bf, acc[et], 0, 0, 0);
    }
    __builtin_amdgcn_s_setprio(0);
    {
      short8 kr = *(const short8*)&kps[km][kg * 8];
      const ushort* ku = (const ushort*)&kr;
#pragma unroll
      for (int j = 0; j < 8; j++) ksp += bf2f(ku[j]);
    }
  }
  float* pb = part + ((size_t)(bh * NS_ + ns) * 5 + mt) * 4096;
#pragma unroll
  for (int et = 0; et < 4; et++)
#pragma unroll
    for (int r = 0; r < 4; r++)
      pb[(w * 16 + quad * 4 + r) * 64 + et * 16 + l16] = acc[et][r];
  kshare[kg][km] = ksp;
  __syncthreads();
  if (tid < 64)
    kpart[((size_t)(bh * NS_ + ns) * 5 + mt) * 64 + tid] =
        kshare[0][tid] + kshare[1][tid] + kshare[2][tid] + kshare[3][tid];
}

// ---------------- reduce partials -> ctxbT bf16 [bh][64 e][288 m] + ksum[bh][PS_] -------------
__global__ __launch_bounds__(256) void ctx_reduce(const float* __restrict__ part,
                                                  const float* __restrict__ kpart,
                                                  ushort* __restrict__ ctxbT,
                                                  float* __restrict__ ksum) {
  const int bh = blockIdx.x, mt = blockIdx.y;
  const int tid = threadIdx.x;
  const int w = tid >> 6, lane = tid & 63;
  for (int oc = w; oc < 8; oc += 4) {
    const int mbase = mt * 64 + oc * 8;
    if (mbase < 288) {
      float s[8] = {0.f, 0.f, 0.f, 0.f, 0.f, 0.f, 0.f, 0.f};
#pragma unroll
      for (int ns = 0; ns < NS_; ns++) {
        const float* pb = part + ((size_t)(bh * NS_ + ns) * 5 + mt) * 4096;
#pragma unroll
        for (int ml = 0; ml < 8; ml++) s[ml] += pb[(oc * 8 + ml) * 64 + lane];
      }
      ushort tmp[8];
#pragma unroll
      for (int ml = 0; ml < 8; ml++) tmp[ml] = f2bf(s[ml]);
      *(short8*)(ctxbT + ((size_t)(bh * 64 + lane)) * 288 + mbase) = *(const short8*)tmp;
    }
  }
  if (tid < 64) {
    float s = 0.f;
#pragma unroll
    for (int ns = 0; ns < NS_; ns++)
      s += kpart[((size_t)(bh * NS_ + ns) * 5 + mt) * 64 + tid];
    ksum[(size_t)bh * PS_ + mt * 64 + tid] = s;
  }
}

// ---------------- fused phi_q + dinv + attn_out ----------------
// R7: q in registers; diag via shfl; coalesced o-write via LDS restage.
// R11: PV loop loads hoisted above the FAVOR epilogue (epilogue VALU covers L2 latency).
__global__ __launch_bounds__(256, 4) void attn_fused(const ushort* __restrict__ qkv,
                                                     const ushort* __restrict__ projp,
                                                     const ushort* __restrict__ ctxbT,
                                                     const float* __restrict__ ksum,
                                                     ushort* __restrict__ o) {
  __shared__ __align__(16) ushort Bs[160 * 64];   // proj staging (2-phase), 20KB
  __shared__ __align__(16) ushort qst[64][40];    // phi_q transpose slabs (per-wave), 5KB
  __shared__ __align__(16) ushort outs[64][64];   // output restage, 8KB
  __shared__ float ks_sh[288];
  const int bh = blockIdx.x, b = bh >> 3, h = bh & 7;
  const int n0 = blockIdx.y * 64;
  const int tid = threadIdx.x;
  const int w = tid >> 6, lane = tid & 63, l16 = lane & 15, quad = lane >> 4;
  const int rl8 = lane >> 3;
  const int lc8 = ((lane & 7) ^ (rl8 & 7)) * 8;
  // stage proj rows 0..159
#pragma unroll
  for (int j = 0; j < 5; j++) {
    const int rb = w * 40 + j * 8;
    async_cp16(projp + (size_t)(rb + rl8) * 64 + lc8, Bs + rb * 64);
  }
  for (int i = tid; i < 288; i += 256) ks_sh[i] = ksum[(size_t)bh * PS_ + i];
  // q A-fragments: lane (l16,quad) holds row (w*16+l16), bytes (s*4+quad)*16
  const ushort* qrow = qkv + (size_t)(b * N_ + n0 + w * 16 + l16) * QKVS_ + h * 64;
  short8 q0 = *(const short8*)(qrow + quad * 8);
  short8 q1 = *(const short8*)(qrow + 32 + quad * 8);
  // diag: partial sum of squares, reduce across quad-lanes (l16, l16+16, +32, +48)
  float dv = 0.f;
  {
    const ushort* u0 = (const ushort*)&q0;
    const ushort* u1 = (const ushort*)&q1;
#pragma unroll
    for (int j = 0; j < 8; j++) {
      float f0 = bf2f(u0[j]), f1 = bf2f(u1[j]);
      dv += f0 * f0 + f1 * f1;
    }
  }
  dv += __shfl_xor(dv, 16);
  dv += __shfl_xor(dv, 32);
  dv *= 0.0625f;                     // 0.5*dn^2 * sum; lane holds diag of row l16
  float dgr[4];
#pragma unroll
  for (int r = 0; r < 4; r++) dgr[r] = __shfl(dv, quad * 4 + r, 16);
  __syncthreads();                    // Bs + ks_sh ready
  floatx4 acc[18];
#pragma unroll
  for (int cf = 0; cf < 18; cf++) acc[cf] = (floatx4){0.f, 0.f, 0.f, 0.f};
  __builtin_amdgcn_s_setprio(1);
#pragma unroll
  for (int s = 0; s < 2; s++) {
    short8 af = s ? q1 : q0;
#pragma unroll
    for (int cf = 0; cf < 10; cf++) {
      const int br = cf * 16 + l16;
      short8 bf = *(const short8*)&Bs[br * 64 + ((s * 4 + quad) ^ (br & 7)) * 8];
      acc[cf] = __builtin_amdgcn_mfma_f32_16x16x32_bf16(af, bf, acc[cf], 0, 0, 0);
    }
  }
  __builtin_amdgcn_s_setprio(0);
  __syncthreads();
#pragma unroll
  for (int j = 0; j < 4; j++) {
    const int rb = w * 32 + j * 8;
    async_cp16(projp + (size_t)(160 + rb + rl8) * 64 + lc8, Bs + rb * 64);
  }
  __syncthreads();
  __builtin_amdgcn_s_setprio(1);
#pragma unroll
  for (int s = 0; s < 2; s++) {
    short8 af = s ? q1 : q0;
#pragma unroll
    for (int cf = 10; cf < 18; cf++) {
      const int br = (cf - 10) * 16 + l16;
      short8 bf = *(const short8*)&Bs[br * 64 + ((s * 4 + quad) ^ (br & 7)) * 8];
      acc[cf] = __builtin_amdgcn_mfma_f32_16x16x32_bf16(af, bf, acc[cf], 0, 0, 0);
    }
  }
  __builtin_amdgcn_s_setprio(0);
  const float dn = 0.35355339059327373f;
  const float ratio = 0.06131393394849658f;
  float mxr[4];
#pragma unroll
  for (int r = 0; r < 4; r++) {
    float v[18];
#pragma unroll
    for (int cf = 0; cf < 18; cf++) {
      const int col = cf * 16 + l16;
      v[cf] = (col < M_) ? dn * acc[cf][r] : -1e30f;
    }
#pragma unroll
    for (int st = 1; st < 18; st <<= 1)
#pragma unroll
      for (int k = 0; k + st < 18; k += 2 * st) v[k] = fmaxf(v[k], v[k + st]);
    float mx = v[0];
    mx = fmaxf(mx, __shfl_xor(mx, 1));
    mx = fmaxf(mx, __shfl_xor(mx, 2));
    mx = fmaxf(mx, __shfl_xor(mx, 4));
    mx = fmaxf(mx, __shfl_xor(mx, 8));
    mxr[r] = mx;
  }
  float dacc[4] = {0.f, 0.f, 0.f, 0.f};
  floatx4 acc2[4] = {};
  const ushort* ctxrow = ctxbT + (size_t)bh * (64 * 288);
  for (int m0 = 0; m0 < 288; m0 += 32) {
    const int cf0 = m0 >> 4;
    // R11: issue the 4 B-fragment loads FIRST -- the FAVOR epilogue below (~8 exp + ds_writes)
    // covers their L2 latency. Same registers as before (bfr was live during MFMA anyway).
    short8 bfr[4];
#pragma unroll
    for (int et = 0; et < 4; et++)
      bfr[et] = *(const short8*)(ctxrow + (size_t)(et * 16 + l16) * 288 + m0 + quad * 8);
    // FAVOR epilogue for this 32-m chunk -> per-wave qst slab (wave-local transpose)
#pragma unroll
    for (int cc = 0; cc < 2; cc++) {
      const int col = m0 + cc * 16 + l16;
      const float kv = ks_sh[col];
#pragma unroll
      for (int r = 0; r < 4; r++) {
        float val = (col < M_) ? ratio * (__expf(dn * acc[cf0 + cc][r] - dgr[r] - mxr[r]) + 1e-4f)
                               : 0.f;
        qst[w * 16 + quad * 4 + r][cc * 16 + l16] = f2bf(val);
        dacc[r] += val * kv;
      }
    }
    short8 af = *(const short8*)&qst[w * 16 + l16][quad * 8];
    __builtin_amdgcn_s_setprio(1);
#pragma unroll
    for (int et = 0; et < 4; et++)
      acc2[et] = __builtin_amdgcn_mfma_f32_16x16x32_bf16(af, bfr[et], acc2[et], 0, 0, 0);
    __builtin_amdgcn_s_setprio(0);
  }
  float di[4];
#pragma unroll
  for (int r = 0; r < 4; r++) {
    float d = dacc[r];
    d += __shfl_xor(d, 1);
    d += __shfl_xor(d, 2);
    d += __shfl_xor(d, 4);
    d += __shfl_xor(d, 8);
    di[r] = 1.f / (d + 1e-8f);
  }
  // restage output through LDS -> 2 coalesced 16B stores per thread (full 128B lines)
#pragma unroll
  for (int r = 0; r < 4; r++)
#pragma unroll
    for (int et = 0; et < 4; et++)
      outs[w * 16 + quad * 4 + r][et * 16 + l16] = f2bf(acc2[et][r] * di[r]);
  // same-wave ds ops are in-order; no barrier needed (per-wave slab)
#pragma unroll
  for (int j = 0; j < 2; j++) {
    const int lr = j * 8 + (lane >> 3);                 // wave-local row 0..15
    short8 ov = *(const short8*)&outs[w * 16 + lr][(lane & 7) * 8];
    *(short8*)(o + (size_t)(b * N_ + n0 + w * 16 + lr) * 512 + h * 64 + (lane & 7) * 8) = ov;
  }
}

// ---------------- depthwise conv K=31, pad 15, + bias + silu; bf16 in/out ----------------
#define TN_ 32
__global__ __launch_bounds__(256) void dwconv_kernel(const ushort* __restrict__ x,
                                                     const float* __restrict__ w,
                                                     const float* __restrict__ bias,
                                                     ushort* __restrict__ out) {
  const int bid = blockIdx.x;
  const int cb = bid & 3;
  const int nb = (bid >> 2) & (N_ / TN_ - 1);
  const int b  = bid >> 8;
  const int c = cb * 256 + threadIdx.x;
  const int n0 = nb * TN_;
  float win[TN_ + 30];
#pragma unroll
  for (int i = 0; i < TN_ + 30; i++) {
    int nn = n0 + i - 15;
    win[i] = (nn >= 0 && nn < N_) ? bf2f(x[(size_t)(b * N_ + nn) * INNER_ + c]) : 0.f;
  }
  float wc[31];
#pragma unroll
  for (int kk = 0; kk < 31; kk++) wc[kk] = w[c * 31 + kk];
  const float bsv = bias[c];
#pragma unroll
  for (int j = 0; j < TN_; j++) {
    float acc = bsv;
#pragma unroll
    for (int kk = 0; kk < 31; kk++) acc += win[j + kk] * wc[kk];
    acc = acc / (1.f + __expf(-acc));
    out[(size_t)(b * N_ + n0 + j) * INNER_ + c] = f2bf(acc);
  }
}

// ---------------- host ----------------
extern "C" void kernel_launch(void* const* d_in, const int* in_sizes, int n_in,
                              void* d_out, int out_size, void* d_ws, size_t ws_size,
                              hipStream_t stream) {
  const float* in_x  = (const float*)d_in[0];
  const float* ln1_g = (const float*)d_in[1];
  const float* ln1_b = (const float*)d_in[2];
  const float* wq    = (const float*)d_in[3];
  const float* bq    = (const float*)d_in[4];
  const float* wk    = (const float*)d_in[5];
  const float* bk    = (const float*)d_in[6];
  const float* wv    = (const float*)d_in[7];
  const float* bv    = (const float*)d_in[8];
  const float* wo    = (const float*)d_in[9];
  const float* bo    = (const float*)d_in[10];
  const float* proj  = (const float*)d_in[11];
  const float* ln2_g = (const float*)d_in[12];
  const float* ln2_b = (const float*)d_in[13];
  const float* pw1_w = (const float*)d_in[14];
  const float* pw1_b = (const float*)d_in[15];
  const float* dw_w  = (const float*)d_in[16];
  const float* dw_b  = (const float*)d_in[17];
  const float* pw2_w = (const float*)d_in[18];
  const float* pw2_b = (const float*)d_in[19];

  char* cur = (char*)d_ws;
  auto alloc = [&](size_t bytes) { char* p = cur; cur += (bytes + 255) & ~(size_t)255; return p; };
  float*  x    = (float*)alloc((size_t)T_ * D_ * 4);
  ushort* p    = (ushort*)alloc((size_t)T_ * INNER_ * 2 * 2);      // glu+conv scratch
  float*  part = (float*)alloc((size_t)32 * NS_ * 5 * 4096 * 4);
  float*  kpart= (float*)alloc((size_t)32 * NS_ * 5 * 64 * 4);
  ushort* ctxb = (ushort*)alloc((size_t)32 * 288 * 64 * 2);        // holds ctx^T [bh][64][288]
  float*  ksum = (float*)alloc((size_t)32 * PS_ * 4);
  ushort* h    = (ushort*)alloc((size_t)T_ * D_ * 2);
  ushort* qkv  = (ushort*)alloc((size_t)T_ * QKVS_ * 2);
  ushort* obuf = (ushort*)alloc((size_t)T_ * D_ * 2);
  ushort* wqkv_b = (ushort*)alloc((size_t)L_LAYERS * QKVS_ * 512 * 2);
  float*  bqkv   = (float*)alloc((size_t)L_LAYERS * QKVS_ * 4);
  // wo_b then p2_b contiguous (single f2bf4_dual output)
  ushort* wo_b = (ushort*)alloc((size_t)L_LAYERS * D_ * D_ * 2 + (size_t)L_LAYERS * D_ * INNER_ * 2);
  ushort* p2_b = wo_b + (size_t)L_LAYERS * D_ * D_;
  ushort* pjp  = (ushort*)alloc((size_t)L_LAYERS * 320 * 64 * 2);
  ushort* p1_b = (ushort*)alloc((size_t)L_LAYERS * 2048 * D_ * 2);
  float*  pb1  = (float*)alloc((size_t)L_LAYERS * 2048 * 4);
  ushort* glu  = p;
  ushort* conv = p + (size_t)T_ * INNER_;

  pack_qkv_w3<<<(3 * L_LAYERS * 512 * 128 + 255) / 256, 256, 0, stream>>>(
      (const float4*)wq, (const float4*)wk, (const float4*)wv, wqkv_b);
  pack_pw1_w<<<(L_LAYERS * 2048 * 128 + 255) / 256, 256, 0, stream>>>((const float4*)pw1_w, p1_b);
  {
    int n1 = L_LAYERS * D_ * D_ / 4;
    int n2 = L_LAYERS * D_ * INNER_ / 4;
    f2bf4_dual<<<(n1 + n2 + 255) / 256, 256, 0, stream>>>(
        (const float4*)wo, n1, (const float4*)pw2_w, n2, wo_b);
  }
  {
    int tot = L_LAYERS * QKVS_ + L_LAYERS * 320 * 64 + L_LAYERS * 2048;
    pack_small<<<(tot + 255) / 256, 256, 0, stream>>>(bq, bk, bv, bqkv, proj, pjp, pw1_b, pb1);
  }

  for (int l = 0; l < L_LAYERS; l++) {
    const ushort* wqkvl = wqkv_b + (size_t)l * QKVS_ * 512;
    const ushort* wol = wo_b + (size_t)l * D_ * D_;
    const ushort* pjl = pjp + (size_t)l * 320 * 64;
    const ushort* p1l = p1_b + (size_t)l * 2048 * D_;
    const ushort* p2l = p2_b + (size_t)l * D_ * INNER_;
    const float*  dwl = dw_w + (size_t)l * INNER_ * 31;
    const float*  dwbl = dw_b + (size_t)l * INNER_;
    const float*  xin = (l == 0) ? in_x : x;
    float* xout = (l == L_LAYERS - 1) ? (float*)d_out : x;

    ln_kernel<<<T_ / 4, 256, 0, stream>>>(xin, ln1_g + l * D_, ln1_b + l * D_, h);
    gemm_mfma<false, true, 0, 512, 3><<<dim3(T_ / 128, QKVS_ / 128), 256, 0, stream>>>(
        h, wqkvl, bqkv + (size_t)l * QKVS_, nullptr, qkv, QKVS_);
    ctx_phi_mfma<<<dim3(32, 5, NS_), 256, 0, stream>>>(qkv, pjl, part, kpart);
    ctx_reduce<<<dim3(32, 5), 256, 0, stream>>>(part, kpart, ctxb, ksum);
    attn_fused<<<dim3(32, 32), 256, 0, stream>>>(qkv, pjl, ctxb, ksum, obuf);
    gemm_sm<512><<<dim3(T_ / 64, 4), 256, 0, stream>>>(
        obuf, wol, bo + l * D_, xin, x, D_);
    ln_kernel<<<T_ / 4, 256, 0, stream>>>(x, ln2_g + l * D_, ln2_b + l * D_, h);
    gemm_mfma<false, true, 1, 512, 2><<<dim3(T_ / 128, 16), 256, 0, stream>>>(
        h, p1l, pb1 + (size_t)l * 2048, nullptr, glu, INNER_);
    dwconv_kernel<<<B_ * (N_ / TN_) * 4, 256, 0, stream>>>(glu, dwl, dwbl, conv);
    gemm_sm<1024><<<dim3(T_ / 64, 4), 256, 0, stream>>>(
        conv, p2l, pw2_b + l * D_, x, xout, D_);
  }
}

// Round 12
// 1105.291 us; speedup vs baseline: 1.0507x; 1.0507x over previous
//
#include <hip/hip_runtime.h>

// PCmer forward: bf16-MFMA; phi_k fused INTO ctx (kp never hits HBM); phi_q+dinv+attn_out fused;
// GLU fused into pw1 (interleaved weights); fused QKV; ksum fused into ctx.
// R1: attn LDS 76->30KB; R2/R3: GEMM counted-vmcnt pipeline; R6: __expf epilogues;
// R7: attn q-in-regs + coalesced o-write; R9: gemm_sm 64x128 for wo/pw2;
// R10: ln wave-per-token (1136.2us = best).
// R11 (REVERTED): PV load hoist re-spilled (VGPR 64, WRITE 46MB scratch traffic).
// R12: ONE change vs R10 -- attn __launch_bounds__(256,4) -> (256,2). Counters show attn has
//      ALWAYS run at 64 VGPR with ~16 floats/thread spilled (WRITE 24.5MB vs 8.4 ideal), yet
//      LDS (35KB) caps residency at 4 blocks/CU anyway (needs only <=128 VGPR). Raising the
//      cap lets the allocator stop spilling at zero occupancy cost.
// L=6, B=4, N=2048, D=512, H=8, DH=64, ID=512, M=266, INNER=1024, K=31.

#define L_LAYERS 6
#define B_ 4
#define N_ 2048
#define D_ 512
#define H_ 8
#define DH_ 64
#define M_ 266
#define INNER_ 1024
#define T_ 8192            // B*N tokens
#define PS_ 320            // padded m stride (zeros in [266,320))
#define QKVS_ 1536         // qkv row stride
#define NS_ 8              // ctx n-splits

typedef __attribute__((ext_vector_type(8))) short short8;
typedef __attribute__((ext_vector_type(4))) float floatx4;

__device__ __forceinline__ ushort f2bf(float f) {
  union { float f; uint u; } v; v.f = f;
  uint r = v.u + 0x7fffu + ((v.u >> 16) & 1u);
  return (ushort)(r >> 16);
}
__device__ __forceinline__ float bf2f(ushort u) {
  union { uint u; float f; } v; v.u = ((uint)u) << 16;
  return v.f;
}
__device__ __forceinline__ float wave_sum(float v) {
#pragma unroll
  for (int m = 1; m < 64; m <<= 1) v += __shfl_xor(v, m);
  return v;
}
// async global->LDS, 16B per lane; dest = wave-uniform base + lane*16 (src per-lane)
__device__ __forceinline__ void async_cp16(const void* g, void* l) {
  __builtin_amdgcn_global_load_lds(
      (const __attribute__((address_space(1))) void*)g,
      (__attribute__((address_space(3))) void*)l, 16, 0, 0);
}

// ---------------- weight packing (consolidated) ----------------
__global__ void f2bf4_dual(const float4* __restrict__ s1, int n1,
                           const float4* __restrict__ s2, int n2,
                           ushort* __restrict__ out) {
  int i = blockIdx.x * 256 + threadIdx.x;
  if (i >= n1 + n2) return;
  float4 v = (i < n1) ? s1[i] : s2[i - n1];
  ushort4 r;
  r.x = f2bf(v.x); r.y = f2bf(v.y); r.z = f2bf(v.z); r.w = f2bf(v.w);
  *(ushort4*)(out + (size_t)i * 4) = r;
}
__global__ void pack_qkv_w3(const float4* __restrict__ wq, const float4* __restrict__ wk,
                            const float4* __restrict__ wv, ushort* __restrict__ dst) {
  int i = blockIdx.x * 256 + threadIdx.x;     // 3*L*512*128
  const int per = L_LAYERS * 512 * 128;
  if (i >= 3 * per) return;
  int seg = i / per;
  int rem = i - seg * per;
  const float4* src = seg == 0 ? wq : (seg == 1 ? wk : wv);
  int l = rem >> 16;
  int r2 = rem & 65535;
  int row = r2 >> 7, c4 = r2 & 127;
  float4 v = src[rem];
  ushort4 r;
  r.x = f2bf(v.x); r.y = f2bf(v.y); r.z = f2bf(v.z); r.w = f2bf(v.w);
  *(ushort4*)(dst + ((size_t)l * QKVS_ + seg * 512 + row) * 512 + c4 * 4) = r;
}
// qkv bias + padded proj + pw1 bias in one kernel (range select)
__global__ void pack_small(const float* __restrict__ bq, const float* __restrict__ bk,
                           const float* __restrict__ bv, float* __restrict__ bqkv,
                           const float* __restrict__ proj, ushort* __restrict__ pjp,
                           const float* __restrict__ pw1b, float* __restrict__ pb1) {
  int i = blockIdx.x * 256 + threadIdx.x;
  const int A = L_LAYERS * QKVS_;            // 9216
  const int Bn = L_LAYERS * 320 * 64;        // 122880
  const int C = L_LAYERS * 2048;             // 12288
  if (i < A) {
    int l = i / QKVS_, c = i % QKVS_;
    bqkv[i] = c < 512 ? bq[l * 512 + c]
                      : (c < 1024 ? bk[l * 512 + c - 512] : bv[l * 512 + c - 1024]);
  } else if (i < A + Bn) {
    int j = i - A;
    int l = j / (320 * 64), rem = j % (320 * 64), m = rem >> 6, kk = rem & 63;
    pjp[j] = (m < M_) ? f2bf(proj[((size_t)l * M_ + m) * 64 + kk]) : (ushort)0;
  } else if (i < A + Bn + C) {
    int j = i - A - Bn;
    int l = j >> 11, cp = j & 2047;
    int s = (cp >> 4) & 1;
    int srow = ((cp >> 5) << 4) + (cp & 15) + s * 1024;
    pb1[j] = pw1b[l * 2048 + srow];
  }
}
// pw1 interleave: out col c' = 32b+16s+j16 -> src row s*1024 + 16b + j16
__global__ void pack_pw1_w(const float4* __restrict__ src, ushort* __restrict__ dst) {
  int i = blockIdx.x * 256 + threadIdx.x;   // L*2048*128
  if (i >= L_LAYERS * 2048 * 128) return;
  int l = i >> 18;
  int rem = i & 262143;
  int cp = rem >> 7, c4 = rem & 127;
  int s = (cp >> 4) & 1;
  int srow = ((cp >> 5) << 4) + (cp & 15) + s * 1024;
  float4 v = src[((size_t)l * 2048 + srow) * 128 + c4];
  ushort4 r;
  r.x = f2bf(v.x); r.y = f2bf(v.y); r.z = f2bf(v.z); r.w = f2bf(v.w);
  *(ushort4*)(dst + ((size_t)l * 2048 + cp) * 512 + c4 * 4) = r;
}

// ---------------- layernorm: wave per token (D=512 = 8 f32/lane), no LDS/barriers ----------
__global__ __launch_bounds__(256) void ln_kernel(const float* __restrict__ x,
                                                 const float* __restrict__ g,
                                                 const float* __restrict__ b,
                                                 ushort* __restrict__ out) {
  const int w = threadIdx.x >> 6, lane = threadIdx.x & 63;
  const int t = blockIdx.x * 4 + w;
  const float4* row = (const float4*)(x + (size_t)t * D_);
  float4 v0 = row[lane * 2];
  float4 v1 = row[lane * 2 + 1];
  float s1 = v0.x + v0.y + v0.z + v0.w + v1.x + v1.y + v1.z + v1.w;
  float s2 = v0.x * v0.x + v0.y * v0.y + v0.z * v0.z + v0.w * v0.w +
             v1.x * v1.x + v1.y * v1.y + v1.z * v1.z + v1.w * v1.w;
  s1 = wave_sum(s1);
  s2 = wave_sum(s2);
  float mu = s1 * (1.f / D_);
  float var = s2 * (1.f / D_) - mu * mu;
  float rs = rsqrtf(var + 1e-5f);
  float4 g0 = ((const float4*)g)[lane * 2];
  float4 g1 = ((const float4*)g)[lane * 2 + 1];
  float4 b0 = ((const float4*)b)[lane * 2];
  float4 b1 = ((const float4*)b)[lane * 2 + 1];
  float vv[8] = {v0.x, v0.y, v0.z, v0.w, v1.x, v1.y, v1.z, v1.w};
  float gg[8] = {g0.x, g0.y, g0.z, g0.w, g1.x, g1.y, g1.z, g1.w};
  float bb[8] = {b0.x, b0.y, b0.z, b0.w, b1.x, b1.y, b1.z, b1.w};
  ushort o8[8];
#pragma unroll
  for (int j = 0; j < 8; j++)
    o8[j] = f2bf((vv[j] - mu) * rs * gg[j] + bb[j]);
  *(short8*)(out + (size_t)t * D_ + lane * 8) = *(const short8*)o8;
}

// ---------------- bf16 MFMA GEMM 128x128: BUFS-deep pipeline, counted vmcnt ----------------
// BUFS=3: depth-2, 48KB (use when grid <= 3 blocks/CU). BUFS=2: depth-1, 32KB (grid = 4/CU).
template <bool HAS_RES, bool OUT_BF16, int ACT, int KT, int BUFS>
__global__ __launch_bounds__(256) void gemm_mfma(const ushort* __restrict__ A,
                                                 const ushort* __restrict__ W,
                                                 const float* __restrict__ bias,
                                                 const float* __restrict__ res,
                                                 void* __restrict__ Cout,
                                                 int ldc) {
  constexpr int NT = KT / 32;
  __shared__ ushort As[BUFS][128 * 32];
  __shared__ ushort Bs[BUFS][128 * 32];
  const int tid = threadIdx.x;
  const int w = tid >> 6, lane = tid & 63;
  const int row0 = blockIdx.x * 128, col0 = blockIdx.y * 128;
  const int rl = lane >> 2;
  const int lc = ((lane & 3) ^ ((lane >> 3) & 3)) * 8;
  const ushort* gA0 = A + (size_t)(row0 + w * 32 + rl) * KT + lc;
  const ushort* gA1 = gA0 + (size_t)16 * KT;
  const ushort* gB0 = W + (size_t)(col0 + w * 32 + rl) * KT + lc;
  const ushort* gB1 = gB0 + (size_t)16 * KT;
  const int m16 = lane & 15, quad = lane >> 4;
  const int awr = (w >> 1) * 64, bwc = (w & 1) * 64;
  floatx4 acc[4][4] = {};

  auto stage = [&](int t, int buf) {
    async_cp16(gA0 + t * 32, As[buf] + w * 1024);
    async_cp16(gA1 + t * 32, As[buf] + w * 1024 + 512);
    async_cp16(gB0 + t * 32, Bs[buf] + w * 1024);
    async_cp16(gB1 + t * 32, Bs[buf] + w * 1024 + 512);
  };
  auto body = [&](int buf, bool bar2) {
    short8 af[4], bfr[4];
#pragma unroll
    for (int i = 0; i < 4; i++) {
      int r = awr + i * 16 + m16;
      af[i] = *(const short8*)&As[buf][r * 32 + (quad ^ ((r >> 1) & 3)) * 8];
    }
#pragma unroll
    for (int j = 0; j < 4; j++) {
      int r = bwc + j * 16 + m16;
      bfr[j] = *(const short8*)&Bs[buf][r * 32 + (quad ^ ((r >> 1) & 3)) * 8];
    }
    if (bar2) {
      asm volatile("s_waitcnt lgkmcnt(0)" ::: "memory");
      __builtin_amdgcn_sched_barrier(0);
      __builtin_amdgcn_s_barrier();
    }
#pragma unroll
    for (int i = 0; i < 4; i++)
#pragma unroll
      for (int j = 0; j < 4; j++)
        acc[i][j] = __builtin_amdgcn_mfma_f32_16x16x32_bf16(af[i], bfr[j], acc[i][j], 0, 0, 0);
  };

  stage(0, 0);
  if (BUFS == 3) stage(1, 1);
  int c = 0;
  for (int t = 0; t < NT - (BUFS - 1); t++) {
    int pf = c + (BUFS - 1); if (pf >= BUFS) pf -= BUFS;
    stage(t + BUFS - 1, pf);
    if (BUFS == 3) { asm volatile("s_waitcnt vmcnt(8)" ::: "memory"); }
    else           { asm volatile("s_waitcnt vmcnt(4)" ::: "memory"); }
    __builtin_amdgcn_s_barrier();
    body(c, true);
    c++; if (c >= BUFS) c -= BUFS;
  }
  if (BUFS == 3) {
    asm volatile("s_waitcnt vmcnt(4)" ::: "memory");
    __builtin_amdgcn_s_barrier();
    body(c, false);
    c++; if (c >= BUFS) c -= BUFS;
  }
  asm volatile("s_waitcnt vmcnt(0)" ::: "memory");
  __builtin_amdgcn_s_barrier();
  body(c, false);

  if (ACT == 0) {
#pragma unroll
    for (int i = 0; i < 4; i++) {
      const int r0 = row0 + awr + i * 16 + quad * 4;
#pragma unroll
      for (int j = 0; j < 4; j++) {
        const int cc = col0 + bwc + j * 16 + m16;
        const float bv = bias[cc];
#pragma unroll
        for (int r = 0; r < 4; r++) {
          float vv = acc[i][j][r] + bv;
          if (HAS_RES) vv += res[(size_t)(r0 + r) * ldc + cc];
          if (OUT_BF16) ((ushort*)Cout)[(size_t)(r0 + r) * ldc + cc] = f2bf(vv);
          else          ((float*)Cout)[(size_t)(r0 + r) * ldc + cc] = vv;
        }
      }
    }
  } else {
    // GLU epilogue on interleaved columns: z = (a+ba)*sigmoid(g+bg)
#pragma unroll
    for (int i = 0; i < 4; i++) {
      const int r0 = row0 + awr + i * 16 + quad * 4;
#pragma unroll
      for (int jp = 0; jp < 2; jp++) {
        const int j = jp * 2;
        const int ca = col0 + bwc + j * 16 + m16;
        const float ba = bias[ca], bg = bias[ca + 16];
        const int oc = ((col0 + bwc) >> 1) + jp * 16 + m16;
#pragma unroll
        for (int r = 0; r < 4; r++) {
          float a = acc[i][j][r] + ba;
          float g = acc[i][j + 1][r] + bg;
          float z = a / (1.f + __expf(-g));
          ((ushort*)Cout)[(size_t)(r0 + r) * ldc + oc] = f2bf(z);
        }
      }
    }
  }
}

// ---------------- bf16 MFMA GEMM 64x128: occupancy variant for wo/pw2 ----------------------
// Grid (T/64, 4) = 512 blocks = 2 blocks/CU (vs 1 for 128^2) -- these GEMMs are latency-bound.
// Wave tile 32x64 (acc[2][4]); 3 loads/wave/stage; vmcnt(6)/(3)/(0); 36KB LDS; fp32 out+res.
template <int KT>
__global__ __launch_bounds__(256) void gemm_sm(const ushort* __restrict__ A,
                                               const ushort* __restrict__ W,
                                               const float* __restrict__ bias,
                                               const float* __restrict__ res,
                                               float* __restrict__ Cout,
                                               int ldc) {
  constexpr int NT = KT / 32;
  __shared__ ushort As[3][64 * 32];
  __shared__ ushort Bs[3][128 * 32];
  const int tid = threadIdx.x;
  const int w = tid >> 6, lane = tid & 63;
  const int row0 = blockIdx.x * 64, col0 = blockIdx.y * 128;
  const int rl = lane >> 2;
  const int lc = ((lane & 3) ^ ((lane >> 3) & 3)) * 8;
  const ushort* gA = A + (size_t)(row0 + w * 16 + rl) * KT + lc;
  const ushort* gB0 = W + (size_t)(col0 + w * 32 + rl) * KT + lc;
  const ushort* gB1 = gB0 + (size_t)16 * KT;
  const int m16 = lane & 15, quad = lane >> 4;
  const int awr = (w >> 1) * 32;
  const int bwc = (w & 1) * 64;
  floatx4 acc[2][4] = {};

  auto stage = [&](int t, int buf) {
    async_cp16(gA + t * 32, As[buf] + w * 512);
    async_cp16(gB0 + t * 32, Bs[buf] + w * 1024);
    async_cp16(gB1 + t * 32, Bs[buf] + w * 1024 + 512);
  };
  auto body = [&](int buf, bool bar2) {
    short8 af[2], bfr[4];
#pragma unroll
    for (int i = 0; i < 2; i++) {
      int r = awr + i * 16 + m16;
      af[i] = *(const short8*)&As[buf][r * 32 + (quad ^ ((r >> 1) & 3)) * 8];
    }
#pragma unroll
    for (int j = 0; j < 4; j++) {
      int r = bwc + j * 16 + m16;
      bfr[j] = *(const short8*)&Bs[buf][r * 32 + (quad ^ ((r >> 1) & 3)) * 8];
    }
    if (bar2) {
      asm volatile("s_waitcnt lgkmcnt(0)" ::: "memory");
      __builtin_amdgcn_sched_barrier(0);
      __builtin_amdgcn_s_barrier();
    }
#pragma unroll
    for (int i = 0; i < 2; i++)
#pragma unroll
      for (int j = 0; j < 4; j++)
        acc[i][j] = __builtin_amdgcn_mfma_f32_16x16x32_bf16(af[i], bfr[j], acc[i][j], 0, 0, 0);
  };

  stage(0, 0);
  stage(1, 1);
  int c = 0;
  for (int t = 0; t < NT - 2; t++) {
    int pf = c + 2; if (pf >= 3) pf -= 3;
    stage(t + 2, pf);
    asm volatile("s_waitcnt vmcnt(6)" ::: "memory");
    __builtin_amdgcn_s_barrier();
    body(c, true);
    c++; if (c >= 3) c -= 3;
  }
  asm volatile("s_waitcnt vmcnt(3)" ::: "memory");
  __builtin_amdgcn_s_barrier();
  body(c, false);
  c++; if (c >= 3) c -= 3;
  asm volatile("s_waitcnt vmcnt(0)" ::: "memory");
  __builtin_amdgcn_s_barrier();
  body(c, false);

#pragma unroll
  for (int i = 0; i < 2; i++) {
    const int r0 = row0 + awr + i * 16 + quad * 4;
#pragma unroll
    for (int j = 0; j < 4; j++) {
      const int cc = col0 + bwc + j * 16 + m16;
      const float bv = bias[cc];
#pragma unroll
      for (int r = 0; r < 4; r++)
        Cout[(size_t)(r0 + r) * ldc + cc] =
            acc[i][j][r] + bv + res[(size_t)(r0 + r) * ldc + cc];
    }
  }
}

// ---------------- ctx with phi_k fused: kp computed in-LDS, never hits HBM ----------------
__global__ __launch_bounds__(256) void ctx_phi_mfma(const ushort* __restrict__ qkv,
                                                    const ushort* __restrict__ projp,
                                                    float* __restrict__ part,
                                                    float* __restrict__ kpart) {
  __shared__ ushort projs[64 * 64];  // proj rows m0..m0+63, XOR-chunk layout
  __shared__ ushort kts[32 * 64];    // raw k tile, XOR-chunk layout
  __shared__ ushort kps[64][40];     // phi^T [m][n swizzled]
  __shared__ ushort vsT[64][40];     // v^T  [e][n swizzled]
  __shared__ float diag_sh[32];
  __shared__ float kshare[4][64];
  const int bh = blockIdx.x, mt = blockIdx.y, ns = blockIdx.z;
  const int b = bh >> 3, h = bh & 7;
  const int m0 = mt * 64;
  const int tid = threadIdx.x;
  const int w = tid >> 6, lane = tid & 63, l16 = lane & 15, quad = lane >> 4;
  const int rl8 = lane >> 3;
  const int lc8 = ((lane & 7) ^ (rl8 & 7)) * 8;
#pragma unroll
  for (int j = 0; j < 2; j++) {
    const int rb = w * 16 + j * 8;
    async_cp16(projp + (size_t)(m0 + rb + rl8) * 64 + lc8, projs + rb * 64);
  }
  const int nn = tid >> 3;
  const int a8 = tid & 7;
  const int gn = nn >> 3, jn = nn & 7;
  const int pc = ((gn ^ (a8 & 3)) << 3) | jn;
  const int km = tid & 63, kg = tid >> 6;
  const float dn = 0.35355339059327373f;
  const float ratio = 0.06131393394849658f;
  floatx4 acc[4] = {};
  float ksp = 0.f;
  for (int nstep = 0; nstep < 2048 / NS_ / 32; nstep++) {
    const int n0 = ns * (2048 / NS_) + nstep * 32;
    {
      const int rb = w * 8;
      async_cp16(qkv + (size_t)(b * N_ + n0 + rb + rl8) * QKVS_ + 512 + h * 64 + lc8,
                 kts + rb * 64);
    }
    uint4 vv = *(const uint4*)(qkv + ((size_t)(b * N_ + n0 + nn)) * QKVS_ + 1024 + h * 64 + a8 * 8);
    __syncthreads();
    {
      const int r = tid >> 3;
      const int c = tid & 7;
      short8 kv8 = *(const short8*)&kts[r * 64 + c * 8];
      const ushort* u = (const ushort*)&kv8;
      float s = 0.f;
#pragma unroll
      for (int j = 0; j < 8; j++) { float f = bf2f(u[j]); s += f * f; }
      s += __shfl_xor(s, 1);
      s += __shfl_xor(s, 2);
      s += __shfl_xor(s, 4);
      if ((tid & 7) == 0) diag_sh[r] = 0.0625f * s;
    }
    {
      const ushort* ve = (const ushort*)&vv;
#pragma unroll
      for (int j = 0; j < 8; j++) vsT[a8 * 8 + j][pc] = ve[j];
    }
    __syncthreads();
    floatx4 pacc[2] = {};
    __builtin_amdgcn_s_setprio(1);
#pragma unroll
    for (int s = 0; s < 2; s++) {
      const int ar = w * 16 + l16;
      short8 af = *(const short8*)&projs[ar * 64 + ((s * 4 + quad) ^ (ar & 7)) * 8];
#pragma unroll
      for (int nj = 0; nj < 2; nj++) {
        const int br = nj * 16 + l16;
        short8 bf = *(const short8*)&kts[br * 64 + ((s * 4 + quad) ^ (br & 7)) * 8];
        pacc[nj] = __builtin_amdgcn_mfma_f32_16x16x32_bf16(af, bf, pacc[nj], 0, 0, 0);
      }
    }
    __builtin_amdgcn_s_setprio(0);
#pragma unroll
    for (int nj = 0; nj < 2; nj++) {
      const int n = nj * 16 + l16;
      const float dgn = diag_sh[n];
#pragma unroll
      for (int r = 0; r < 4; r++) {
        const int m = w * 16 + quad * 4 + r;
        float val = (m0 + m < M_) ? ratio * __expf(dn * pacc[nj][r] - dgn + 1e-4f) : 0.f;
        kps[m][(((n >> 3) ^ ((m >> 3) & 3)) << 3) | (n & 7)] = f2bf(val);
      }
    }
    __syncthreads();
    const int am = w * 16 + l16;
    const int apg = quad ^ ((am >> 3) & 3);
    short8 af = *(const short8*)&kps[am][apg * 8];
    __builtin_amdgcn_s_setprio(1);
#pragma unroll
    for (int et = 0; et < 4; et++) {
      const int be = et * 16 + l16;
      const int bpg = quad ^ ((be >> 3) & 3);
      short8 bf = *(const short8*)&vsT[be][bpg * 8];
      acc[et] = __builtin_amdgcn_mfma_f32_16x16x32_bf16(af, bf, acc[et], 0, 0, 0);
    }
    __builtin_amdgcn_s_setprio(0);
    {
      short8 kr = *(const short8*)&kps[km][kg * 8];
      const ushort* ku = (const ushort*)&kr;
#pragma unroll
      for (int j = 0; j < 8; j++) ksp += bf2f(ku[j]);
    }
  }
  float* pb = part + ((size_t)(bh * NS_ + ns) * 5 + mt) * 4096;
#pragma unroll
  for (int et = 0; et < 4; et++)
#pragma unroll
    for (int r = 0; r < 4; r++)
      pb[(w * 16 + quad * 4 + r) * 64 + et * 16 + l16] = acc[et][r];
  kshare[kg][km] = ksp;
  __syncthreads();
  if (tid < 64)
    kpart[((size_t)(bh * NS_ + ns) * 5 + mt) * 64 + tid] =
        kshare[0][tid] + kshare[1][tid] + kshare[2][tid] + kshare[3][tid];
}

// ---------------- reduce partials -> ctxbT bf16 [bh][64 e][288 m] + ksum[bh][PS_] -------------
__global__ __launch_bounds__(256) void ctx_reduce(const float* __restrict__ part,
                                                  const float* __restrict__ kpart,
                                                  ushort* __restrict__ ctxbT,
                                                  float* __restrict__ ksum) {
  const int bh = blockIdx.x, mt = blockIdx.y;
  const int tid = threadIdx.x;
  const int w = tid >> 6, lane = tid & 63;
  for (int oc = w; oc < 8; oc += 4) {
    const int mbase = mt * 64 + oc * 8;
    if (mbase < 288) {
      float s[8] = {0.f, 0.f, 0.f, 0.f, 0.f, 0.f, 0.f, 0.f};
#pragma unroll
      for (int ns = 0; ns < NS_; ns++) {
        const float* pb = part + ((size_t)(bh * NS_ + ns) * 5 + mt) * 4096;
#pragma unroll
        for (int ml = 0; ml < 8; ml++) s[ml] += pb[(oc * 8 + ml) * 64 + lane];
      }
      ushort tmp[8];
#pragma unroll
      for (int ml = 0; ml < 8; ml++) tmp[ml] = f2bf(s[ml]);
      *(short8*)(ctxbT + ((size_t)(bh * 64 + lane)) * 288 + mbase) = *(const short8*)tmp;
    }
  }
  if (tid < 64) {
    float s = 0.f;
#pragma unroll
    for (int ns = 0; ns < NS_; ns++)
      s += kpart[((size_t)(bh * NS_ + ns) * 5 + mt) * 64 + tid];
    ksum[(size_t)bh * PS_ + mt * 64 + tid] = s;
  }
}

// ---------------- fused phi_q + dinv + attn_out (R10 structure; R12: launch_bounds 256,2) ----
__global__ __launch_bounds__(256, 2) void attn_fused(const ushort* __restrict__ qkv,
                                                     const ushort* __restrict__ projp,
                                                     const ushort* __restrict__ ctxbT,
                                                     const float* __restrict__ ksum,
                                                     ushort* __restrict__ o) {
  __shared__ __align__(16) ushort Bs[160 * 64];   // proj staging (2-phase), 20KB
  __shared__ __align__(16) ushort qst[64][40];    // phi_q transpose slabs (per-wave), 5KB
  __shared__ __align__(16) ushort outs[64][64];   // output restage, 8KB
  __shared__ float ks_sh[288];
  const int bh = blockIdx.x, b = bh >> 3, h = bh & 7;
  const int n0 = blockIdx.y * 64;
  const int tid = threadIdx.x;
  const int w = tid >> 6, lane = tid & 63, l16 = lane & 15, quad = lane >> 4;
  const int rl8 = lane >> 3;
  const int lc8 = ((lane & 7) ^ (rl8 & 7)) * 8;
  // stage proj rows 0..159
#pragma unroll
  for (int j = 0; j < 5; j++) {
    const int rb = w * 40 + j * 8;
    async_cp16(projp + (size_t)(rb + rl8) * 64 + lc8, Bs + rb * 64);
  }
  for (int i = tid; i < 288; i += 256) ks_sh[i] = ksum[(size_t)bh * PS_ + i];
  // q A-fragments: lane (l16,quad) holds row (w*16+l16), bytes (s*4+quad)*16
  const ushort* qrow = qkv + (size_t)(b * N_ + n0 + w * 16 + l16) * QKVS_ + h * 64;
  short8 q0 = *(const short8*)(qrow + quad * 8);
  short8 q1 = *(const short8*)(qrow + 32 + quad * 8);
  // diag: partial sum of squares, reduce across quad-lanes (l16, l16+16, +32, +48)
  float dv = 0.f;
  {
    const ushort* u0 = (const ushort*)&q0;
    const ushort* u1 = (const ushort*)&q1;
#pragma unroll
    for (int j = 0; j < 8; j++) {
      float f0 = bf2f(u0[j]), f1 = bf2f(u1[j]);
      dv += f0 * f0 + f1 * f1;
    }
  }
  dv += __shfl_xor(dv, 16);
  dv += __shfl_xor(dv, 32);
  dv *= 0.0625f;                     // 0.5*dn^2 * sum; lane holds diag of row l16
  float dgr[4];
#pragma unroll
  for (int r = 0; r < 4; r++) dgr[r] = __shfl(dv, quad * 4 + r, 16);
  __syncthreads();                    // Bs + ks_sh ready
  floatx4 acc[18];
#pragma unroll
  for (int cf = 0; cf < 18; cf++) acc[cf] = (floatx4){0.f, 0.f, 0.f, 0.f};
  __builtin_amdgcn_s_setprio(1);
#pragma unroll
  for (int s = 0; s < 2; s++) {
    short8 af = s ? q1 : q0;
#pragma unroll
    for (int cf = 0; cf < 10; cf++) {
      const int br = cf * 16 + l16;
      short8 bf = *(const short8*)&Bs[br * 64 + ((s * 4 + quad) ^ (br & 7)) * 8];
      acc[cf] = __builtin_amdgcn_mfma_f32_16x16x32_bf16(af, bf, acc[cf], 0, 0, 0);
    }
  }
  __builtin_amdgcn_s_setprio(0);
  __syncthreads();
#pragma unroll
  for (int j = 0; j < 4; j++) {
    const int rb = w * 32 + j * 8;
    async_cp16(projp + (size_t)(160 + rb + rl8) * 64 + lc8, Bs + rb * 64);
  }
  __syncthreads();
  __builtin_amdgcn_s_setprio(1);
#pragma unroll
  for (int s = 0; s < 2; s++) {
    short8 af = s ? q1 : q0;
#pragma unroll
    for (int cf = 10; cf < 18; cf++) {
      const int br = (cf - 10) * 16 + l16;
      short8 bf = *(const short8*)&Bs[br * 64 + ((s * 4 + quad) ^ (br & 7)) * 8];
      acc[cf] = __builtin_amdgcn_mfma_f32_16x16x32_bf16(af, bf, acc[cf], 0, 0, 0);
    }
  }
  __builtin_amdgcn_s_setprio(0);
  const float dn = 0.35355339059327373f;
  const float ratio = 0.06131393394849658f;
  float mxr[4];
#pragma unroll
  for (int r = 0; r < 4; r++) {
    float v[18];
#pragma unroll
    for (int cf = 0; cf < 18; cf++) {
      const int col = cf * 16 + l16;
      v[cf] = (col < M_) ? dn * acc[cf][r] : -1e30f;
    }
#pragma unroll
    for (int st = 1; st < 18; st <<= 1)
#pragma unroll
      for (int k = 0; k + st < 18; k += 2 * st) v[k] = fmaxf(v[k], v[k + st]);
    float mx = v[0];
    mx = fmaxf(mx, __shfl_xor(mx, 1));
    mx = fmaxf(mx, __shfl_xor(mx, 2));
    mx = fmaxf(mx, __shfl_xor(mx, 4));
    mx = fmaxf(mx, __shfl_xor(mx, 8));
    mxr[r] = mx;
  }
  float dacc[4] = {0.f, 0.f, 0.f, 0.f};
  floatx4 acc2[4] = {};
  const ushort* ctxrow = ctxbT + (size_t)bh * (64 * 288);
  for (int m0 = 0; m0 < 288; m0 += 32) {
    const int cf0 = m0 >> 4;
    // FAVOR epilogue for this 32-m chunk -> per-wave qst slab (wave-local transpose)
#pragma unroll
    for (int cc = 0; cc < 2; cc++) {
      const int col = m0 + cc * 16 + l16;
      const float kv = ks_sh[col];
#pragma unroll
      for (int r = 0; r < 4; r++) {
        float val = (col < M_) ? ratio * (__expf(dn * acc[cf0 + cc][r] - dgr[r] - mxr[r]) + 1e-4f)
                               : 0.f;
        qst[w * 16 + quad * 4 + r][cc * 16 + l16] = f2bf(val);
        dacc[r] += val * kv;
      }
    }
    short8 af = *(const short8*)&qst[w * 16 + l16][quad * 8];
    __builtin_amdgcn_s_setprio(1);
#pragma unroll
    for (int et = 0; et < 4; et++) {
      short8 bf = *(const short8*)(ctxrow + (size_t)(et * 16 + l16) * 288 + m0 + quad * 8);
      acc2[et] = __builtin_amdgcn_mfma_f32_16x16x32_bf16(af, bf, acc2[et], 0, 0, 0);
    }
    __builtin_amdgcn_s_setprio(0);
  }
  float di[4];
#pragma unroll
  for (int r = 0; r < 4; r++) {
    float d = dacc[r];
    d += __shfl_xor(d, 1);
    d += __shfl_xor(d, 2);
    d += __shfl_xor(d, 4);
    d += __shfl_xor(d, 8);
    di[r] = 1.f / (d + 1e-8f);
  }
  // restage output through LDS -> 2 coalesced 16B stores per thread (full 128B lines)
#pragma unroll
  for (int r = 0; r < 4; r++)
#pragma unroll
    for (int et = 0; et < 4; et++)
      outs[w * 16 + quad * 4 + r][et * 16 + l16] = f2bf(acc2[et][r] * di[r]);
  // same-wave ds ops are in-order; no barrier needed (per-wave slab)
#pragma unroll
  for (int j = 0; j < 2; j++) {
    const int lr = j * 8 + (lane >> 3);                 // wave-local row 0..15
    short8 ov = *(const short8*)&outs[w * 16 + lr][(lane & 7) * 8];
    *(short8*)(o + (size_t)(b * N_ + n0 + w * 16 + lr) * 512 + h * 64 + (lane & 7) * 8) = ov;
  }
}

// ---------------- depthwise conv K=31, pad 15, + bias + silu; bf16 in/out ----------------
#define TN_ 32
__global__ __launch_bounds__(256) void dwconv_kernel(const ushort* __restrict__ x,
                                                     const float* __restrict__ w,
                                                     const float* __restrict__ bias,
                                                     ushort* __restrict__ out) {
  const int bid = blockIdx.x;
  const int cb = bid & 3;
  const int nb = (bid >> 2) & (N_ / TN_ - 1);
  const int b  = bid >> 8;
  const int c = cb * 256 + threadIdx.x;
  const int n0 = nb * TN_;
  float win[TN_ + 30];
#pragma unroll
  for (int i = 0; i < TN_ + 30; i++) {
    int nn = n0 + i - 15;
    win[i] = (nn >= 0 && nn < N_) ? bf2f(x[(size_t)(b * N_ + nn) * INNER_ + c]) : 0.f;
  }
  float wc[31];
#pragma unroll
  for (int kk = 0; kk < 31; kk++) wc[kk] = w[c * 31 + kk];
  const float bsv = bias[c];
#pragma unroll
  for (int j = 0; j < TN_; j++) {
    float acc = bsv;
#pragma unroll
    for (int kk = 0; kk < 31; kk++) acc += win[j + kk] * wc[kk];
    acc = acc / (1.f + __expf(-acc));
    out[(size_t)(b * N_ + n0 + j) * INNER_ + c] = f2bf(acc);
  }
}

// ---------------- host ----------------
extern "C" void kernel_launch(void* const* d_in, const int* in_sizes, int n_in,
                              void* d_out, int out_size, void* d_ws, size_t ws_size,
                              hipStream_t stream) {
  const float* in_x  = (const float*)d_in[0];
  const float* ln1_g = (const float*)d_in[1];
  const float* ln1_b = (const float*)d_in[2];
  const float* wq    = (const float*)d_in[3];
  const float* bq    = (const float*)d_in[4];
  const float* wk    = (const float*)d_in[5];
  const float* bk    = (const float*)d_in[6];
  const float* wv    = (const float*)d_in[7];
  const float* bv    = (const float*)d_in[8];
  const float* wo    = (const float*)d_in[9];
  const float* bo    = (const float*)d_in[10];
  const float* proj  = (const float*)d_in[11];
  const float* ln2_g = (const float*)d_in[12];
  const float* ln2_b = (const float*)d_in[13];
  const float* pw1_w = (const float*)d_in[14];
  const float* pw1_b = (const float*)d_in[15];
  const float* dw_w  = (const float*)d_in[16];
  const float* dw_b  = (const float*)d_in[17];
  const float* pw2_w = (const float*)d_in[18];
  const float* pw2_b = (const float*)d_in[19];

  char* cur = (char*)d_ws;
  auto alloc = [&](size_t bytes) { char* p = cur; cur += (bytes + 255) & ~(size_t)255; return p; };
  float*  x    = (float*)alloc((size_t)T_ * D_ * 4);
  ushort* p    = (ushort*)alloc((size_t)T_ * INNER_ * 2 * 2);      // glu+conv scratch
  float*  part = (float*)alloc((size_t)32 * NS_ * 5 * 4096 * 4);
  float*  kpart= (float*)alloc((size_t)32 * NS_ * 5 * 64 * 4);
  ushort* ctxb = (ushort*)alloc((size_t)32 * 288 * 64 * 2);        // holds ctx^T [bh][64][288]
  float*  ksum = (float*)alloc((size_t)32 * PS_ * 4);
  ushort* h    = (ushort*)alloc((size_t)T_ * D_ * 2);
  ushort* qkv  = (ushort*)alloc((size_t)T_ * QKVS_ * 2);
  ushort* obuf = (ushort*)alloc((size_t)T_ * D_ * 2);
  ushort* wqkv_b = (ushort*)alloc((size_t)L_LAYERS * QKVS_ * 512 * 2);
  float*  bqkv   = (float*)alloc((size_t)L_LAYERS * QKVS_ * 4);
  // wo_b then p2_b contiguous (single f2bf4_dual output)
  ushort* wo_b = (ushort*)alloc((size_t)L_LAYERS * D_ * D_ * 2 + (size_t)L_LAYERS * D_ * INNER_ * 2);
  ushort* p2_b = wo_b + (size_t)L_LAYERS * D_ * D_;
  ushort* pjp  = (ushort*)alloc((size_t)L_LAYERS * 320 * 64 * 2);
  ushort* p1_b = (ushort*)alloc((size_t)L_LAYERS * 2048 * D_ * 2);
  float*  pb1  = (float*)alloc((size_t)L_LAYERS * 2048 * 4);
  ushort* glu  = p;
  ushort* conv = p + (size_t)T_ * INNER_;

  pack_qkv_w3<<<(3 * L_LAYERS * 512 * 128 + 255) / 256, 256, 0, stream>>>(
      (const float4*)wq, (const float4*)wk, (const float4*)wv, wqkv_b);
  pack_pw1_w<<<(L_LAYERS * 2048 * 128 + 255) / 256, 256, 0, stream>>>((const float4*)pw1_w, p1_b);
  {
    int n1 = L_LAYERS * D_ * D_ / 4;
    int n2 = L_LAYERS * D_ * INNER_ / 4;
    f2bf4_dual<<<(n1 + n2 + 255) / 256, 256, 0, stream>>>(
        (const float4*)wo, n1, (const float4*)pw2_w, n2, wo_b);
  }
  {
    int tot = L_LAYERS * QKVS_ + L_LAYERS * 320 * 64 + L_LAYERS * 2048;
    pack_small<<<(tot + 255) / 256, 256, 0, stream>>>(bq, bk, bv, bqkv, proj, pjp, pw1_b, pb1);
  }

  for (int l = 0; l < L_LAYERS; l++) {
    const ushort* wqkvl = wqkv_b + (size_t)l * QKVS_ * 512;
    const ushort* wol = wo_b + (size_t)l * D_ * D_;
    const ushort* pjl = pjp + (size_t)l * 320 * 64;
    const ushort* p1l = p1_b + (size_t)l * 2048 * D_;
    const ushort* p2l = p2_b + (size_t)l * D_ * INNER_;
    const float*  dwl = dw_w + (size_t)l * INNER_ * 31;
    const float*  dwbl = dw_b + (size_t)l * INNER_;
    const float*  xin = (l == 0) ? in_x : x;
    float* xout = (l == L_LAYERS - 1) ? (float*)d_out : x;

    ln_kernel<<<T_ / 4, 256, 0, stream>>>(xin, ln1_g + l * D_, ln1_b + l * D_, h);
    gemm_mfma<false, true, 0, 512, 3><<<dim3(T_ / 128, QKVS_ / 128), 256, 0, stream>>>(
        h, wqkvl, bqkv + (size_t)l * QKVS_, nullptr, qkv, QKVS_);
    ctx_phi_mfma<<<dim3(32, 5, NS_), 256, 0, stream>>>(qkv, pjl, part, kpart);
    ctx_reduce<<<dim3(32, 5), 256, 0, stream>>>(part, kpart, ctxb, ksum);
    attn_fused<<<dim3(32, 32), 256, 0, stream>>>(qkv, pjl, ctxb, ksum, obuf);
    gemm_sm<512><<<dim3(T_ / 64, 4), 256, 0, stream>>>(
        obuf, wol, bo + l * D_, xin, x, D_);
    ln_kernel<<<T_ / 4, 256, 0, stream>>>(x, ln2_g + l * D_, ln2_b + l * D_, h);
    gemm_mfma<false, true, 1, 512, 2><<<dim3(T_ / 128, 16), 256, 0, stream>>>(
        h, p1l, pb1 + (size_t)l * 2048, nullptr, glu, INNER_);
    dwconv_kernel<<<B_ * (N_ / TN_) * 4, 256, 0, stream>>>(glu, dwl, dwbl, conv);
    gemm_sm<1024><<<dim3(T_ / 64, 4), 256, 0, stream>>>(
        conv, p2l, pw2_b + l * D_, x, xout, D_);
  }
}

// Round 13
// 1095.075 us; speedup vs baseline: 1.0605x; 1.0093x over previous
//
#include <hip/hip_runtime.h>

// PCmer forward: bf16-MFMA; phi_k fused INTO ctx (kp never hits HBM); phi_q+dinv+attn_out fused;
// GLU fused into pw1 (interleaved weights); fused QKV; ksum fused into ctx.
// R1: attn LDS 76->30KB; R2/R3: GEMM counted-vmcnt pipeline; R6: __expf epilogues;
// R7: attn q-in-regs + coalesced o-write; R9: gemm_sm 64x128 for wo/pw2;
// R10: ln wave-per-token; R12: attn launch_bounds (256,2) -- un-spilled attn (1105.3us = best).
// R13: ONE change vs R12 -- re-apply R11's PV load hoist (loads before FAVOR epilogue).
//      R11 failed ONLY because the 64-VGPR cap made the longer live range spill; R12 removed
//      that cap. Now the hoist costs 16 live VGPRs against a 256 budget. Watch FETCH/WRITE:
//      if they rise above R12 levels, the allocator spilled again -> revert.
// L=6, B=4, N=2048, D=512, H=8, DH=64, ID=512, M=266, INNER=1024, K=31.

#define L_LAYERS 6
#define B_ 4
#define N_ 2048
#define D_ 512
#define H_ 8
#define DH_ 64
#define M_ 266
#define INNER_ 1024
#define T_ 8192            // B*N tokens
#define PS_ 320            // padded m stride (zeros in [266,320))
#define QKVS_ 1536         // qkv row stride
#define NS_ 8              // ctx n-splits

typedef __attribute__((ext_vector_type(8))) short short8;
typedef __attribute__((ext_vector_type(4))) float floatx4;

__device__ __forceinline__ ushort f2bf(float f) {
  union { float f; uint u; } v; v.f = f;
  uint r = v.u + 0x7fffu + ((v.u >> 16) & 1u);
  return (ushort)(r >> 16);
}
__device__ __forceinline__ float bf2f(ushort u) {
  union { uint u; float f; } v; v.u = ((uint)u) << 16;
  return v.f;
}
__device__ __forceinline__ float wave_sum(float v) {
#pragma unroll
  for (int m = 1; m < 64; m <<= 1) v += __shfl_xor(v, m);
  return v;
}
// async global->LDS, 16B per lane; dest = wave-uniform base + lane*16 (src per-lane)
__device__ __forceinline__ void async_cp16(const void* g, void* l) {
  __builtin_amdgcn_global_load_lds(
      (const __attribute__((address_space(1))) void*)g,
      (__attribute__((address_space(3))) void*)l, 16, 0, 0);
}

// ---------------- weight packing (consolidated) ----------------
__global__ void f2bf4_dual(const float4* __restrict__ s1, int n1,
                           const float4* __restrict__ s2, int n2,
                           ushort* __restrict__ out) {
  int i = blockIdx.x * 256 + threadIdx.x;
  if (i >= n1 + n2) return;
  float4 v = (i < n1) ? s1[i] : s2[i - n1];
  ushort4 r;
  r.x = f2bf(v.x); r.y = f2bf(v.y); r.z = f2bf(v.z); r.w = f2bf(v.w);
  *(ushort4*)(out + (size_t)i * 4) = r;
}
__global__ void pack_qkv_w3(const float4* __restrict__ wq, const float4* __restrict__ wk,
                            const float4* __restrict__ wv, ushort* __restrict__ dst) {
  int i = blockIdx.x * 256 + threadIdx.x;     // 3*L*512*128
  const int per = L_LAYERS * 512 * 128;
  if (i >= 3 * per) return;
  int seg = i / per;
  int rem = i - seg * per;
  const float4* src = seg == 0 ? wq : (seg == 1 ? wk : wv);
  int l = rem >> 16;
  int r2 = rem & 65535;
  int row = r2 >> 7, c4 = r2 & 127;
  float4 v = src[rem];
  ushort4 r;
  r.x = f2bf(v.x); r.y = f2bf(v.y); r.z = f2bf(v.z); r.w = f2bf(v.w);
  *(ushort4*)(dst + ((size_t)l * QKVS_ + seg * 512 + row) * 512 + c4 * 4) = r;
}
// qkv bias + padded proj + pw1 bias in one kernel (range select)
__global__ void pack_small(const float* __restrict__ bq, const float* __restrict__ bk,
                           const float* __restrict__ bv, float* __restrict__ bqkv,
                           const float* __restrict__ proj, ushort* __restrict__ pjp,
                           const float* __restrict__ pw1b, float* __restrict__ pb1) {
  int i = blockIdx.x * 256 + threadIdx.x;
  const int A = L_LAYERS * QKVS_;            // 9216
  const int Bn = L_LAYERS * 320 * 64;        // 122880
  const int C = L_LAYERS * 2048;             // 12288
  if (i < A) {
    int l = i / QKVS_, c = i % QKVS_;
    bqkv[i] = c < 512 ? bq[l * 512 + c]
                      : (c < 1024 ? bk[l * 512 + c - 512] : bv[l * 512 + c - 1024]);
  } else if (i < A + Bn) {
    int j = i - A;
    int l = j / (320 * 64), rem = j % (320 * 64), m = rem >> 6, kk = rem & 63;
    pjp[j] = (m < M_) ? f2bf(proj[((size_t)l * M_ + m) * 64 + kk]) : (ushort)0;
  } else if (i < A + Bn + C) {
    int j = i - A - Bn;
    int l = j >> 11, cp = j & 2047;
    int s = (cp >> 4) & 1;
    int srow = ((cp >> 5) << 4) + (cp & 15) + s * 1024;
    pb1[j] = pw1b[l * 2048 + srow];
  }
}
// pw1 interleave: out col c' = 32b+16s+j16 -> src row s*1024 + 16b + j16
__global__ void pack_pw1_w(const float4* __restrict__ src, ushort* __restrict__ dst) {
  int i = blockIdx.x * 256 + threadIdx.x;   // L*2048*128
  if (i >= L_LAYERS * 2048 * 128) return;
  int l = i >> 18;
  int rem = i & 262143;
  int cp = rem >> 7, c4 = rem & 127;
  int s = (cp >> 4) & 1;
  int srow = ((cp >> 5) << 4) + (cp & 15) + s * 1024;
  float4 v = src[((size_t)l * 2048 + srow) * 128 + c4];
  ushort4 r;
  r.x = f2bf(v.x); r.y = f2bf(v.y); r.z = f2bf(v.z); r.w = f2bf(v.w);
  *(ushort4*)(dst + ((size_t)l * 2048 + cp) * 512 + c4 * 4) = r;
}

// ---------------- layernorm: wave per token (D=512 = 8 f32/lane), no LDS/barriers ----------
__global__ __launch_bounds__(256) void ln_kernel(const float* __restrict__ x,
                                                 const float* __restrict__ g,
                                                 const float* __restrict__ b,
                                                 ushort* __restrict__ out) {
  const int w = threadIdx.x >> 6, lane = threadIdx.x & 63;
  const int t = blockIdx.x * 4 + w;
  const float4* row = (const float4*)(x + (size_t)t * D_);
  float4 v0 = row[lane * 2];
  float4 v1 = row[lane * 2 + 1];
  float s1 = v0.x + v0.y + v0.z + v0.w + v1.x + v1.y + v1.z + v1.w;
  float s2 = v0.x * v0.x + v0.y * v0.y + v0.z * v0.z + v0.w * v0.w +
             v1.x * v1.x + v1.y * v1.y + v1.z * v1.z + v1.w * v1.w;
  s1 = wave_sum(s1);
  s2 = wave_sum(s2);
  float mu = s1 * (1.f / D_);
  float var = s2 * (1.f / D_) - mu * mu;
  float rs = rsqrtf(var + 1e-5f);
  float4 g0 = ((const float4*)g)[lane * 2];
  float4 g1 = ((const float4*)g)[lane * 2 + 1];
  float4 b0 = ((const float4*)b)[lane * 2];
  float4 b1 = ((const float4*)b)[lane * 2 + 1];
  float vv[8] = {v0.x, v0.y, v0.z, v0.w, v1.x, v1.y, v1.z, v1.w};
  float gg[8] = {g0.x, g0.y, g0.z, g0.w, g1.x, g1.y, g1.z, g1.w};
  float bb[8] = {b0.x, b0.y, b0.z, b0.w, b1.x, b1.y, b1.z, b1.w};
  ushort o8[8];
#pragma unroll
  for (int j = 0; j < 8; j++)
    o8[j] = f2bf((vv[j] - mu) * rs * gg[j] + bb[j]);
  *(short8*)(out + (size_t)t * D_ + lane * 8) = *(const short8*)o8;
}

// ---------------- bf16 MFMA GEMM 128x128: BUFS-deep pipeline, counted vmcnt ----------------
// BUFS=3: depth-2, 48KB (use when grid <= 3 blocks/CU). BUFS=2: depth-1, 32KB (grid = 4/CU).
template <bool HAS_RES, bool OUT_BF16, int ACT, int KT, int BUFS>
__global__ __launch_bounds__(256) void gemm_mfma(const ushort* __restrict__ A,
                                                 const ushort* __restrict__ W,
                                                 const float* __restrict__ bias,
                                                 const float* __restrict__ res,
                                                 void* __restrict__ Cout,
                                                 int ldc) {
  constexpr int NT = KT / 32;
  __shared__ ushort As[BUFS][128 * 32];
  __shared__ ushort Bs[BUFS][128 * 32];
  const int tid = threadIdx.x;
  const int w = tid >> 6, lane = tid & 63;
  const int row0 = blockIdx.x * 128, col0 = blockIdx.y * 128;
  const int rl = lane >> 2;
  const int lc = ((lane & 3) ^ ((lane >> 3) & 3)) * 8;
  const ushort* gA0 = A + (size_t)(row0 + w * 32 + rl) * KT + lc;
  const ushort* gA1 = gA0 + (size_t)16 * KT;
  const ushort* gB0 = W + (size_t)(col0 + w * 32 + rl) * KT + lc;
  const ushort* gB1 = gB0 + (size_t)16 * KT;
  const int m16 = lane & 15, quad = lane >> 4;
  const int awr = (w >> 1) * 64, bwc = (w & 1) * 64;
  floatx4 acc[4][4] = {};

  auto stage = [&](int t, int buf) {
    async_cp16(gA0 + t * 32, As[buf] + w * 1024);
    async_cp16(gA1 + t * 32, As[buf] + w * 1024 + 512);
    async_cp16(gB0 + t * 32, Bs[buf] + w * 1024);
    async_cp16(gB1 + t * 32, Bs[buf] + w * 1024 + 512);
  };
  auto body = [&](int buf, bool bar2) {
    short8 af[4], bfr[4];
#pragma unroll
    for (int i = 0; i < 4; i++) {
      int r = awr + i * 16 + m16;
      af[i] = *(const short8*)&As[buf][r * 32 + (quad ^ ((r >> 1) & 3)) * 8];
    }
#pragma unroll
    for (int j = 0; j < 4; j++) {
      int r = bwc + j * 16 + m16;
      bfr[j] = *(const short8*)&Bs[buf][r * 32 + (quad ^ ((r >> 1) & 3)) * 8];
    }
    if (bar2) {
      asm volatile("s_waitcnt lgkmcnt(0)" ::: "memory");
      __builtin_amdgcn_sched_barrier(0);
      __builtin_amdgcn_s_barrier();
    }
#pragma unroll
    for (int i = 0; i < 4; i++)
#pragma unroll
      for (int j = 0; j < 4; j++)
        acc[i][j] = __builtin_amdgcn_mfma_f32_16x16x32_bf16(af[i], bfr[j], acc[i][j], 0, 0, 0);
  };

  stage(0, 0);
  if (BUFS == 3) stage(1, 1);
  int c = 0;
  for (int t = 0; t < NT - (BUFS - 1); t++) {
    int pf = c + (BUFS - 1); if (pf >= BUFS) pf -= BUFS;
    stage(t + BUFS - 1, pf);
    if (BUFS == 3) { asm volatile("s_waitcnt vmcnt(8)" ::: "memory"); }
    else           { asm volatile("s_waitcnt vmcnt(4)" ::: "memory"); }
    __builtin_amdgcn_s_barrier();
    body(c, true);
    c++; if (c >= BUFS) c -= BUFS;
  }
  if (BUFS == 3) {
    asm volatile("s_waitcnt vmcnt(4)" ::: "memory");
    __builtin_amdgcn_s_barrier();
    body(c, false);
    c++; if (c >= BUFS) c -= BUFS;
  }
  asm volatile("s_waitcnt vmcnt(0)" ::: "memory");
  __builtin_amdgcn_s_barrier();
  body(c, false);

  if (ACT == 0) {
#pragma unroll
    for (int i = 0; i < 4; i++) {
      const int r0 = row0 + awr + i * 16 + quad * 4;
#pragma unroll
      for (int j = 0; j < 4; j++) {
        const int cc = col0 + bwc + j * 16 + m16;
        const float bv = bias[cc];
#pragma unroll
        for (int r = 0; r < 4; r++) {
          float vv = acc[i][j][r] + bv;
          if (HAS_RES) vv += res[(size_t)(r0 + r) * ldc + cc];
          if (OUT_BF16) ((ushort*)Cout)[(size_t)(r0 + r) * ldc + cc] = f2bf(vv);
          else          ((float*)Cout)[(size_t)(r0 + r) * ldc + cc] = vv;
        }
      }
    }
  } else {
    // GLU epilogue on interleaved columns: z = (a+ba)*sigmoid(g+bg)
#pragma unroll
    for (int i = 0; i < 4; i++) {
      const int r0 = row0 + awr + i * 16 + quad * 4;
#pragma unroll
      for (int jp = 0; jp < 2; jp++) {
        const int j = jp * 2;
        const int ca = col0 + bwc + j * 16 + m16;
        const float ba = bias[ca], bg = bias[ca + 16];
        const int oc = ((col0 + bwc) >> 1) + jp * 16 + m16;
#pragma unroll
        for (int r = 0; r < 4; r++) {
          float a = acc[i][j][r] + ba;
          float g = acc[i][j + 1][r] + bg;
          float z = a / (1.f + __expf(-g));
          ((ushort*)Cout)[(size_t)(r0 + r) * ldc + oc] = f2bf(z);
        }
      }
    }
  }
}

// ---------------- bf16 MFMA GEMM 64x128: occupancy variant for wo/pw2 ----------------------
template <int KT>
__global__ __launch_bounds__(256) void gemm_sm(const ushort* __restrict__ A,
                                               const ushort* __restrict__ W,
                                               const float* __restrict__ bias,
                                               const float* __restrict__ res,
                                               float* __restrict__ Cout,
                                               int ldc) {
  constexpr int NT = KT / 32;
  __shared__ ushort As[3][64 * 32];
  __shared__ ushort Bs[3][128 * 32];
  const int tid = threadIdx.x;
  const int w = tid >> 6, lane = tid & 63;
  const int row0 = blockIdx.x * 64, col0 = blockIdx.y * 128;
  const int rl = lane >> 2;
  const int lc = ((lane & 3) ^ ((lane >> 3) & 3)) * 8;
  const ushort* gA = A + (size_t)(row0 + w * 16 + rl) * KT + lc;
  const ushort* gB0 = W + (size_t)(col0 + w * 32 + rl) * KT + lc;
  const ushort* gB1 = gB0 + (size_t)16 * KT;
  const int m16 = lane & 15, quad = lane >> 4;
  const int awr = (w >> 1) * 32;
  const int bwc = (w & 1) * 64;
  floatx4 acc[2][4] = {};

  auto stage = [&](int t, int buf) {
    async_cp16(gA + t * 32, As[buf] + w * 512);
    async_cp16(gB0 + t * 32, Bs[buf] + w * 1024);
    async_cp16(gB1 + t * 32, Bs[buf] + w * 1024 + 512);
  };
  auto body = [&](int buf, bool bar2) {
    short8 af[2], bfr[4];
#pragma unroll
    for (int i = 0; i < 2; i++) {
      int r = awr + i * 16 + m16;
      af[i] = *(const short8*)&As[buf][r * 32 + (quad ^ ((r >> 1) & 3)) * 8];
    }
#pragma unroll
    for (int j = 0; j < 4; j++) {
      int r = bwc + j * 16 + m16;
      bfr[j] = *(const short8*)&Bs[buf][r * 32 + (quad ^ ((r >> 1) & 3)) * 8];
    }
    if (bar2) {
      asm volatile("s_waitcnt lgkmcnt(0)" ::: "memory");
      __builtin_amdgcn_sched_barrier(0);
      __builtin_amdgcn_s_barrier();
    }
#pragma unroll
    for (int i = 0; i < 2; i++)
#pragma unroll
      for (int j = 0; j < 4; j++)
        acc[i][j] = __builtin_amdgcn_mfma_f32_16x16x32_bf16(af[i], bfr[j], acc[i][j], 0, 0, 0);
  };

  stage(0, 0);
  stage(1, 1);
  int c = 0;
  for (int t = 0; t < NT - 2; t++) {
    int pf = c + 2; if (pf >= 3) pf -= 3;
    stage(t + 2, pf);
    asm volatile("s_waitcnt vmcnt(6)" ::: "memory");
    __builtin_amdgcn_s_barrier();
    body(c, true);
    c++; if (c >= 3) c -= 3;
  }
  asm volatile("s_waitcnt vmcnt(3)" ::: "memory");
  __builtin_amdgcn_s_barrier();
  body(c, false);
  c++; if (c >= 3) c -= 3;
  asm volatile("s_waitcnt vmcnt(0)" ::: "memory");
  __builtin_amdgcn_s_barrier();
  body(c, false);

#pragma unroll
  for (int i = 0; i < 2; i++) {
    const int r0 = row0 + awr + i * 16 + quad * 4;
#pragma unroll
    for (int j = 0; j < 4; j++) {
      const int cc = col0 + bwc + j * 16 + m16;
      const float bv = bias[cc];
#pragma unroll
      for (int r = 0; r < 4; r++)
        Cout[(size_t)(r0 + r) * ldc + cc] =
            acc[i][j][r] + bv + res[(size_t)(r0 + r) * ldc + cc];
    }
  }
}

// ---------------- ctx with phi_k fused: kp computed in-LDS, never hits HBM ----------------
__global__ __launch_bounds__(256) void ctx_phi_mfma(const ushort* __restrict__ qkv,
                                                    const ushort* __restrict__ projp,
                                                    float* __restrict__ part,
                                                    float* __restrict__ kpart) {
  __shared__ ushort projs[64 * 64];  // proj rows m0..m0+63, XOR-chunk layout
  __shared__ ushort kts[32 * 64];    // raw k tile, XOR-chunk layout
  __shared__ ushort kps[64][40];     // phi^T [m][n swizzled]
  __shared__ ushort vsT[64][40];     // v^T  [e][n swizzled]
  __shared__ float diag_sh[32];
  __shared__ float kshare[4][64];
  const int bh = blockIdx.x, mt = blockIdx.y, ns = blockIdx.z;
  const int b = bh >> 3, h = bh & 7;
  const int m0 = mt * 64;
  const int tid = threadIdx.x;
  const int w = tid >> 6, lane = tid & 63, l16 = lane & 15, quad = lane >> 4;
  const int rl8 = lane >> 3;
  const int lc8 = ((lane & 7) ^ (rl8 & 7)) * 8;
#pragma unroll
  for (int j = 0; j < 2; j++) {
    const int rb = w * 16 + j * 8;
    async_cp16(projp + (size_t)(m0 + rb + rl8) * 64 + lc8, projs + rb * 64);
  }
  const int nn = tid >> 3;
  const int a8 = tid & 7;
  const int gn = nn >> 3, jn = nn & 7;
  const int pc = ((gn ^ (a8 & 3)) << 3) | jn;
  const int km = tid & 63, kg = tid >> 6;
  const float dn = 0.35355339059327373f;
  const float ratio = 0.06131393394849658f;
  floatx4 acc[4] = {};
  float ksp = 0.f;
  for (int nstep = 0; nstep < 2048 / NS_ / 32; nstep++) {
    const int n0 = ns * (2048 / NS_) + nstep * 32;
    {
      const int rb = w * 8;
      async_cp16(qkv + (size_t)(b * N_ + n0 + rb + rl8) * QKVS_ + 512 + h * 64 + lc8,
                 kts + rb * 64);
    }
    uint4 vv = *(const uint4*)(qkv + ((size_t)(b * N_ + n0 + nn)) * QKVS_ + 1024 + h * 64 + a8 * 8);
    __syncthreads();
    {
      const int r = tid >> 3;
      const int c = tid & 7;
      short8 kv8 = *(const short8*)&kts[r * 64 + c * 8];
      const ushort* u = (const ushort*)&kv8;
      float s = 0.f;
#pragma unroll
      for (int j = 0; j < 8; j++) { float f = bf2f(u[j]); s += f * f; }
      s += __shfl_xor(s, 1);
      s += __shfl_xor(s, 2);
      s += __shfl_xor(s, 4);
      if ((tid & 7) == 0) diag_sh[r] = 0.0625f * s;
    }
    {
      const ushort* ve = (const ushort*)&vv;
#pragma unroll
      for (int j = 0; j < 8; j++) vsT[a8 * 8 + j][pc] = ve[j];
    }
    __syncthreads();
    floatx4 pacc[2] = {};
    __builtin_amdgcn_s_setprio(1);
#pragma unroll
    for (int s = 0; s < 2; s++) {
      const int ar = w * 16 + l16;
      short8 af = *(const short8*)&projs[ar * 64 + ((s * 4 + quad) ^ (ar & 7)) * 8];
#pragma unroll
      for (int nj = 0; nj < 2; nj++) {
        const int br = nj * 16 + l16;
        short8 bf = *(const short8*)&kts[br * 64 + ((s * 4 + quad) ^ (br & 7)) * 8];
        pacc[nj] = __builtin_amdgcn_mfma_f32_16x16x32_bf16(af, bf, pacc[nj], 0, 0, 0);
      }
    }
    __builtin_amdgcn_s_setprio(0);
#pragma unroll
    for (int nj = 0; nj < 2; nj++) {
      const int n = nj * 16 + l16;
      const float dgn = diag_sh[n];
#pragma unroll
      for (int r = 0; r < 4; r++) {
        const int m = w * 16 + quad * 4 + r;
        float val = (m0 + m < M_) ? ratio * __expf(dn * pacc[nj][r] - dgn + 1e-4f) : 0.f;
        kps[m][(((n >> 3) ^ ((m >> 3) & 3)) << 3) | (n & 7)] = f2bf(val);
      }
    }
    __syncthreads();
    const int am = w * 16 + l16;
    const int apg = quad ^ ((am >> 3) & 3);
    short8 af = *(const short8*)&kps[am][apg * 8];
    __builtin_amdgcn_s_setprio(1);
#pragma unroll
    for (int et = 0; et < 4; et++) {
      const int be = et * 16 + l16;
      const int bpg = quad ^ ((be >> 3) & 3);
      short8 bf = *(const short8*)&vsT[be][bpg * 8];
      acc[et] = __builtin_amdgcn_mfma_f32_16x16x32_bf16(af, bf, acc[et], 0, 0, 0);
    }
    __builtin_amdgcn_s_setprio(0);
    {
      short8 kr = *(const short8*)&kps[km][kg * 8];
      const ushort* ku = (const ushort*)&kr;
#pragma unroll
      for (int j = 0; j < 8; j++) ksp += bf2f(ku[j]);
    }
  }
  float* pb = part + ((size_t)(bh * NS_ + ns) * 5 + mt) * 4096;
#pragma unroll
  for (int et = 0; et < 4; et++)
#pragma unroll
    for (int r = 0; r < 4; r++)
      pb[(w * 16 + quad * 4 + r) * 64 + et * 16 + l16] = acc[et][r];
  kshare[kg][km] = ksp;
  __syncthreads();
  if (tid < 64)
    kpart[((size_t)(bh * NS_ + ns) * 5 + mt) * 64 + tid] =
        kshare[0][tid] + kshare[1][tid] + kshare[2][tid] + kshare[3][tid];
}

// ---------------- reduce partials -> ctxbT bf16 [bh][64 e][288 m] + ksum[bh][PS_] -------------
__global__ __launch_bounds__(256) void ctx_reduce(const float* __restrict__ part,
                                                  const float* __restrict__ kpart,
                                                  ushort* __restrict__ ctxbT,
                                                  float* __restrict__ ksum) {
  const int bh = blockIdx.x, mt = blockIdx.y;
  const int tid = threadIdx.x;
  const int w = tid >> 6, lane = tid & 63;
  for (int oc = w; oc < 8; oc += 4) {
    const int mbase = mt * 64 + oc * 8;
    if (mbase < 288) {
      float s[8] = {0.f, 0.f, 0.f, 0.f, 0.f, 0.f, 0.f, 0.f};
#pragma unroll
      for (int ns = 0; ns < NS_; ns++) {
        const float* pb = part + ((size_t)(bh * NS_ + ns) * 5 + mt) * 4096;
#pragma unroll
        for (int ml = 0; ml < 8; ml++) s[ml] += pb[(oc * 8 + ml) * 64 + lane];
      }
      ushort tmp[8];
#pragma unroll
      for (int ml = 0; ml < 8; ml++) tmp[ml] = f2bf(s[ml]);
      *(short8*)(ctxbT + ((size_t)(bh * 64 + lane)) * 288 + mbase) = *(const short8*)tmp;
    }
  }
  if (tid < 64) {
    float s = 0.f;
#pragma unroll
    for (int ns = 0; ns < NS_; ns++)
      s += kpart[((size_t)(bh * NS_ + ns) * 5 + mt) * 64 + tid];
    ksum[(size_t)bh * PS_ + mt * 64 + tid] = s;
  }
}

// ---------------- fused phi_q + dinv + attn_out (launch_bounds 256,2; R13: PV load hoist) ----
__global__ __launch_bounds__(256, 2) void attn_fused(const ushort* __restrict__ qkv,
                                                     const ushort* __restrict__ projp,
                                                     const ushort* __restrict__ ctxbT,
                                                     const float* __restrict__ ksum,
                                                     ushort* __restrict__ o) {
  __shared__ __align__(16) ushort Bs[160 * 64];   // proj staging (2-phase), 20KB
  __shared__ __align__(16) ushort qst[64][40];    // phi_q transpose slabs (per-wave), 5KB
  __shared__ __align__(16) ushort outs[64][64];   // output restage, 8KB
  __shared__ float ks_sh[288];
  const int bh = blockIdx.x, b = bh >> 3, h = bh & 7;
  const int n0 = blockIdx.y * 64;
  const int tid = threadIdx.x;
  const int w = tid >> 6, lane = tid & 63, l16 = lane & 15, quad = lane >> 4;
  const int rl8 = lane >> 3;
  const int lc8 = ((lane & 7) ^ (rl8 & 7)) * 8;
  // stage proj rows 0..159
#pragma unroll
  for (int j = 0; j < 5; j++) {
    const int rb = w * 40 + j * 8;
    async_cp16(projp + (size_t)(rb + rl8) * 64 + lc8, Bs + rb * 64);
  }
  for (int i = tid; i < 288; i += 256) ks_sh[i] = ksum[(size_t)bh * PS_ + i];
  // q A-fragments: lane (l16,quad) holds row (w*16+l16), bytes (s*4+quad)*16
  const ushort* qrow = qkv + (size_t)(b * N_ + n0 + w * 16 + l16) * QKVS_ + h * 64;
  short8 q0 = *(const short8*)(qrow + quad * 8);
  short8 q1 = *(const short8*)(qrow + 32 + quad * 8);
  // diag: partial sum of squares, reduce across quad-lanes (l16, l16+16, +32, +48)
  float dv = 0.f;
  {
    const ushort* u0 = (const ushort*)&q0;
    const ushort* u1 = (const ushort*)&q1;
#pragma unroll
    for (int j = 0; j < 8; j++) {
      float f0 = bf2f(u0[j]), f1 = bf2f(u1[j]);
      dv += f0 * f0 + f1 * f1;
    }
  }
  dv += __shfl_xor(dv, 16);
  dv += __shfl_xor(dv, 32);
  dv *= 0.0625f;                     // 0.5*dn^2 * sum; lane holds diag of row l16
  float dgr[4];
#pragma unroll
  for (int r = 0; r < 4; r++) dgr[r] = __shfl(dv, quad * 4 + r, 16);
  __syncthreads();                    // Bs + ks_sh ready
  floatx4 acc[18];
#pragma unroll
  for (int cf = 0; cf < 18; cf++) acc[cf] = (floatx4){0.f, 0.f, 0.f, 0.f};
  __builtin_amdgcn_s_setprio(1);
#pragma unroll
  for (int s = 0; s < 2; s++) {
    short8 af = s ? q1 : q0;
#pragma unroll
    for (int cf = 0; cf < 10; cf++) {
      const int br = cf * 16 + l16;
      short8 bf = *(const short8*)&Bs[br * 64 + ((s * 4 + quad) ^ (br & 7)) * 8];
      acc[cf] = __builtin_amdgcn_mfma_f32_16x16x32_bf16(af, bf, acc[cf], 0, 0, 0);
    }
  }
  __builtin_amdgcn_s_setprio(0);
  __syncthreads();
#pragma unroll
  for (int j = 0; j < 4; j++) {
    const int rb = w * 32 + j * 8;
    async_cp16(projp + (size_t)(160 + rb + rl8) * 64 + lc8, Bs + rb * 64);
  }
  __syncthreads();
  __builtin_amdgcn_s_setprio(1);
#pragma unroll
  for (int s = 0; s < 2; s++) {
    short8 af = s ? q1 : q0;
#pragma unroll
    for (int cf = 10; cf < 18; cf++) {
      const int br = (cf - 10) * 16 + l16;
      short8 bf = *(const short8*)&Bs[br * 64 + ((s * 4 + quad) ^ (br & 7)) * 8];
      acc[cf] = __builtin_amdgcn_mfma_f32_16x16x32_bf16(af, bf, acc[cf], 0, 0, 0);
    }
  }
  __builtin_amdgcn_s_setprio(0);
  const float dn = 0.35355339059327373f;
  const float ratio = 0.06131393394849658f;
  float mxr[4];
#pragma unroll
  for (int r = 0; r < 4; r++) {
    float v[18];
#pragma unroll
    for (int cf = 0; cf < 18; cf++) {
      const int col = cf * 16 + l16;
      v[cf] = (col < M_) ? dn * acc[cf][r] : -1e30f;
    }
#pragma unroll
    for (int st = 1; st < 18; st <<= 1)
#pragma unroll
      for (int k = 0; k + st < 18; k += 2 * st) v[k] = fmaxf(v[k], v[k + st]);
    float mx = v[0];
    mx = fmaxf(mx, __shfl_xor(mx, 1));
    mx = fmaxf(mx, __shfl_xor(mx, 2));
    mx = fmaxf(mx, __shfl_xor(mx, 4));
    mx = fmaxf(mx, __shfl_xor(mx, 8));
    mxr[r] = mx;
  }
  float dacc[4] = {0.f, 0.f, 0.f, 0.f};
  floatx4 acc2[4] = {};
  const ushort* ctxrow = ctxbT + (size_t)bh * (64 * 288);
  for (int m0 = 0; m0 < 288; m0 += 32) {
    const int cf0 = m0 >> 4;
    // R13: issue the 4 B-fragment loads FIRST -- the FAVOR epilogue below covers L2 latency.
    // Safe now: launch_bounds(256,2) gives the allocator headroom (R11 spilled at the 64 cap).
    short8 bfr[4];
#pragma unroll
    for (int et = 0; et < 4; et++)
      bfr[et] = *(const short8*)(ctxrow + (size_t)(et * 16 + l16) * 288 + m0 + quad * 8);
    // FAVOR epilogue for this 32-m chunk -> per-wave qst slab (wave-local transpose)
#pragma unroll
    for (int cc = 0; cc < 2; cc++) {
      const int col = m0 + cc * 16 + l16;
      const float kv = ks_sh[col];
#pragma unroll
      for (int r = 0; r < 4; r++) {
        float val = (col < M_) ? ratio * (__expf(dn * acc[cf0 + cc][r] - dgr[r] - mxr[r]) + 1e-4f)
                               : 0.f;
        qst[w * 16 + quad * 4 + r][cc * 16 + l16] = f2bf(val);
        dacc[r] += val * kv;
      }
    }
    short8 af = *(const short8*)&qst[w * 16 + l16][quad * 8];
    __builtin_amdgcn_s_setprio(1);
#pragma unroll
    for (int et = 0; et < 4; et++)
      acc2[et] = __builtin_amdgcn_mfma_f32_16x16x32_bf16(af, bfr[et], acc2[et], 0, 0, 0);
    __builtin_amdgcn_s_setprio(0);
  }
  float di[4];
#pragma unroll
  for (int r = 0; r < 4; r++) {
    float d = dacc[r];
    d += __shfl_xor(d, 1);
    d += __shfl_xor(d, 2);
    d += __shfl_xor(d, 4);
    d += __shfl_xor(d, 8);
    di[r] = 1.f / (d + 1e-8f);
  }
  // restage output through LDS -> 2 coalesced 16B stores per thread (full 128B lines)
#pragma unroll
  for (int r = 0; r < 4; r++)
#pragma unroll
    for (int et = 0; et < 4; et++)
      outs[w * 16 + quad * 4 + r][et * 16 + l16] = f2bf(acc2[et][r] * di[r]);
  // same-wave ds ops are in-order; no barrier needed (per-wave slab)
#pragma unroll
  for (int j = 0; j < 2; j++) {
    const int lr = j * 8 + (lane >> 3);                 // wave-local row 0..15
    short8 ov = *(const short8*)&outs[w * 16 + lr][(lane & 7) * 8];
    *(short8*)(o + (size_t)(b * N_ + n0 + w * 16 + lr) * 512 + h * 64 + (lane & 7) * 8) = ov;
  }
}

// ---------------- depthwise conv K=31, pad 15, + bias + silu; bf16 in/out ----------------
#define TN_ 32
__global__ __launch_bounds__(256) void dwconv_kernel(const ushort* __restrict__ x,
                                                     const float* __restrict__ w,
                                                     const float* __restrict__ bias,
                                                     ushort* __restrict__ out) {
  const int bid = blockIdx.x;
  const int cb = bid & 3;
  const int nb = (bid >> 2) & (N_ / TN_ - 1);
  const int b  = bid >> 8;
  const int c = cb * 256 + threadIdx.x;
  const int n0 = nb * TN_;
  float win[TN_ + 30];
#pragma unroll
  for (int i = 0; i < TN_ + 30; i++) {
    int nn = n0 + i - 15;
    win[i] = (nn >= 0 && nn < N_) ? bf2f(x[(size_t)(b * N_ + nn) * INNER_ + c]) : 0.f;
  }
  float wc[31];
#pragma unroll
  for (int kk = 0; kk < 31; kk++) wc[kk] = w[c * 31 + kk];
  const float bsv = bias[c];
#pragma unroll
  for (int j = 0; j < TN_; j++) {
    float acc = bsv;
#pragma unroll
    for (int kk = 0; kk < 31; kk++) acc += win[j + kk] * wc[kk];
    acc = acc / (1.f + __expf(-acc));
    out[(size_t)(b * N_ + n0 + j) * INNER_ + c] = f2bf(acc);
  }
}

// ---------------- host ----------------
extern "C" void kernel_launch(void* const* d_in, const int* in_sizes, int n_in,
                              void* d_out, int out_size, void* d_ws, size_t ws_size,
                              hipStream_t stream) {
  const float* in_x  = (const float*)d_in[0];
  const float* ln1_g = (const float*)d_in[1];
  const float* ln1_b = (const float*)d_in[2];
  const float* wq    = (const float*)d_in[3];
  const float* bq    = (const float*)d_in[4];
  const float* wk    = (const float*)d_in[5];
  const float* bk    = (const float*)d_in[6];
  const float* wv    = (const float*)d_in[7];
  const float* bv    = (const float*)d_in[8];
  const float* wo    = (const float*)d_in[9];
  const float* bo    = (const float*)d_in[10];
  const float* proj  = (const float*)d_in[11];
  const float* ln2_g = (const float*)d_in[12];
  const float* ln2_b = (const float*)d_in[13];
  const float* pw1_w = (const float*)d_in[14];
  const float* pw1_b = (const float*)d_in[15];
  const float* dw_w  = (const float*)d_in[16];
  const float* dw_b  = (const float*)d_in[17];
  const float* pw2_w = (const float*)d_in[18];
  const float* pw2_b = (const float*)d_in[19];

  char* cur = (char*)d_ws;
  auto alloc = [&](size_t bytes) { char* p = cur; cur += (bytes + 255) & ~(size_t)255; return p; };
  float*  x    = (float*)alloc((size_t)T_ * D_ * 4);
  ushort* p    = (ushort*)alloc((size_t)T_ * INNER_ * 2 * 2);      // glu+conv scratch
  float*  part = (float*)alloc((size_t)32 * NS_ * 5 * 4096 * 4);
  float*  kpart= (float*)alloc((size_t)32 * NS_ * 5 * 64 * 4);
  ushort* ctxb = (ushort*)alloc((size_t)32 * 288 * 64 * 2);        // holds ctx^T [bh][64][288]
  float*  ksum = (float*)alloc((size_t)32 * PS_ * 4);
  ushort* h    = (ushort*)alloc((size_t)T_ * D_ * 2);
  ushort* qkv  = (ushort*)alloc((size_t)T_ * QKVS_ * 2);
  ushort* obuf = (ushort*)alloc((size_t)T_ * D_ * 2);
  ushort* wqkv_b = (ushort*)alloc((size_t)L_LAYERS * QKVS_ * 512 * 2);
  float*  bqkv   = (float*)alloc((size_t)L_LAYERS * QKVS_ * 4);
  // wo_b then p2_b contiguous (single f2bf4_dual output)
  ushort* wo_b = (ushort*)alloc((size_t)L_LAYERS * D_ * D_ * 2 + (size_t)L_LAYERS * D_ * INNER_ * 2);
  ushort* p2_b = wo_b + (size_t)L_LAYERS * D_ * D_;
  ushort* pjp  = (ushort*)alloc((size_t)L_LAYERS * 320 * 64 * 2);
  ushort* p1_b = (ushort*)alloc((size_t)L_LAYERS * 2048 * D_ * 2);
  float*  pb1  = (float*)alloc((size_t)L_LAYERS * 2048 * 4);
  ushort* glu  = p;
  ushort* conv = p + (size_t)T_ * INNER_;

  pack_qkv_w3<<<(3 * L_LAYERS * 512 * 128 + 255) / 256, 256, 0, stream>>>(
      (const float4*)wq, (const float4*)wk, (const float4*)wv, wqkv_b);
  pack_pw1_w<<<(L_LAYERS * 2048 * 128 + 255) / 256, 256, 0, stream>>>((const float4*)pw1_w, p1_b);
  {
    int n1 = L_LAYERS * D_ * D_ / 4;
    int n2 = L_LAYERS * D_ * INNER_ / 4;
    f2bf4_dual<<<(n1 + n2 + 255) / 256, 256, 0, stream>>>(
        (const float4*)wo, n1, (const float4*)pw2_w, n2, wo_b);
  }
  {
    int tot = L_LAYERS * QKVS_ + L_LAYERS * 320 * 64 + L_LAYERS * 2048;
    pack_small<<<(tot + 255) / 256, 256, 0, stream>>>(bq, bk, bv, bqkv, proj, pjp, pw1_b, pb1);
  }

  for (int l = 0; l < L_LAYERS; l++) {
    const ushort* wqkvl = wqkv_b + (size_t)l * QKVS_ * 512;
    const ushort* wol = wo_b + (size_t)l * D_ * D_;
    const ushort* pjl = pjp + (size_t)l * 320 * 64;
    const ushort* p1l = p1_b + (size_t)l * 2048 * D_;
    const ushort* p2l = p2_b + (size_t)l * D_ * INNER_;
    const float*  dwl = dw_w + (size_t)l * INNER_ * 31;
    const float*  dwbl = dw_b + (size_t)l * INNER_;
    const float*  xin = (l == 0) ? in_x : x;
    float* xout = (l == L_LAYERS - 1) ? (float*)d_out : x;

    ln_kernel<<<T_ / 4, 256, 0, stream>>>(xin, ln1_g + l * D_, ln1_b + l * D_, h);
    gemm_mfma<false, true, 0, 512, 3><<<dim3(T_ / 128, QKVS_ / 128), 256, 0, stream>>>(
        h, wqkvl, bqkv + (size_t)l * QKVS_, nullptr, qkv, QKVS_);
    ctx_phi_mfma<<<dim3(32, 5, NS_), 256, 0, stream>>>(qkv, pjl, part, kpart);
    ctx_reduce<<<dim3(32, 5), 256, 0, stream>>>(part, kpart, ctxb, ksum);
    attn_fused<<<dim3(32, 32), 256, 0, stream>>>(qkv, pjl, ctxb, ksum, obuf);
    gemm_sm<512><<<dim3(T_ / 64, 4), 256, 0, stream>>>(
        obuf, wol, bo + l * D_, xin, x, D_);
    ln_kernel<<<T_ / 4, 256, 0, stream>>>(x, ln2_g + l * D_, ln2_b + l * D_, h);
    gemm_mfma<false, true, 1, 512, 2><<<dim3(T_ / 128, 16), 256, 0, stream>>>(
        h, p1l, pb1 + (size_t)l * 2048, nullptr, glu, INNER_);
    dwconv_kernel<<<B_ * (N_ / TN_) * 4, 256, 0, stream>>>(glu, dwl, dwbl, conv);
    gemm_sm<1024><<<dim3(T_ / 64, 4), 256, 0, stream>>>(
        conv, p2l, pw2_b + l * D_, x, xout, D_);
  }
}